// Round 1
// baseline (742.245 us; speedup 1.0000x reference)
//
#include <hip/hip_runtime.h>

typedef unsigned short u16;
typedef unsigned int   u32;
typedef _Float16       f16;

typedef f16   f16x8 __attribute__((ext_vector_type(8)));
typedef float f32x4 __attribute__((ext_vector_type(4)));

#define LSTR 40  // LDS row stride (elements) for 128x32 conv tiles; 40*2B=80B keeps 16B alignment

__device__ __forceinline__ f32x4 mfma16(f16x8 a, f16x8 b, f32x4 c){
  return __builtin_amdgcn_mfma_f32_16x16x32_f16(a, b, c, 0, 0, 0);
}

// ============ 1. per-(b,c) spatial mean / rstd for content & style ============
__global__ __launch_bounds__(256) void k_mvn_stats(
    const float* __restrict__ content, const float* __restrict__ style,
    float* __restrict__ stats)
{
  const int src = blockIdx.x >> 11;     // 0=content, 1=style
  const int row = blockIdx.x & 2047;    // b*512 + c
  const float* xp = (src ? style : content) + (size_t)row * 4096;
  const int t = threadIdx.x;
  double s = 0.0, ss = 0.0;
  for(int i = t * 4; i < 4096; i += 1024){
    float4 v = *(const float4*)(xp + i);
    s  += (double)v.x + (double)v.y + (double)v.z + (double)v.w;
    ss += (double)v.x * v.x + (double)v.y * v.y + (double)v.z * v.z + (double)v.w * v.w;
  }
  #pragma unroll
  for(int off = 32; off > 0; off >>= 1){
    s  += __shfl_xor(s, off);
    ss += __shfl_xor(ss, off);
  }
  __shared__ double sh[8];
  const int wid = t >> 6;
  if((t & 63) == 0){ sh[wid] = s; sh[4 + wid] = ss; }
  __syncthreads();
  if(t == 0){
    double S  = sh[0] + sh[1] + sh[2] + sh[3];
    double SS = sh[4] + sh[5] + sh[6] + sh[7];
    float mean = (float)(S * (1.0 / 4096.0));
    float var  = (float)((SS - S * S * (1.0 / 4096.0)) * (1.0 / 4095.0)); // ddof=1
    stats[src * 4096 + row] = mean;
    stats[src * 4096 + 2048 + row] = rsqrtf(var + 1e-5f);
  }
}

// ============ 2. conv1x1 GEMM, fp16 MFMA single-pass, fp16 output ============
// out[o,s] = sum_c W[o,c]*X[c,s](normalized?) + bias[o]
__global__ __launch_bounds__(256) void k_conv_h(
    const float* __restrict__ X, const float* __restrict__ Wm,
    const float* __restrict__ bias, const float* __restrict__ stats,
    int norm_off, f16* __restrict__ Out)
{
  const int b = blockIdx.z;
  const int o0 = blockIdx.y * 128;
  const int s0 = blockIdx.x * 128;
  const float* Xb = X + (size_t)b * 512 * 4096;
  f16* Ob = Out + (size_t)b * 512 * 4096;
  __shared__ f16 As[128 * LSTR];
  __shared__ f16 Bs[128 * LSTR];
  const int t = threadIdx.x;
  const int lane = t & 63, wid = t >> 6;
  const int wm = (wid >> 1) * 64, wn = (wid & 1) * 64;
  const int lr = lane & 15, lg = lane >> 4;
  f32x4 acc[4][4] = {};
  for(int kk = 0; kk < 512; kk += 32){
    __syncthreads();
    // A tile: W[o0..o0+128][kk..kk+32] f32->f16
    #pragma unroll
    for(int rep = 0; rep < 4; rep++){
      int q = t + 256 * rep;
      int row = q >> 3, c4 = q & 7;
      float4 w4 = *(const float4*)(Wm + (size_t)(o0 + row) * 512 + kk + c4 * 4);
      f16* dst = As + row * LSTR + c4 * 4;
      dst[0] = (f16)w4.x; dst[1] = (f16)w4.y; dst[2] = (f16)w4.z; dst[3] = (f16)w4.w;
    }
    // B tile: X[kk..kk+32][s0..s0+128] f32 -> f16, transposed into [n][k]
    #pragma unroll
    for(int rep = 0; rep < 4; rep++){
      int q = t + 256 * rep;
      int kr = q >> 5, s4 = q & 31;
      int c = kk + kr;
      float4 x4 = *(const float4*)(Xb + (size_t)c * 4096 + s0 + s4 * 4);
      if(norm_off >= 0){
        float mean = stats[norm_off + b * 512 + c];
        float rstd = stats[norm_off + 2048 + b * 512 + c];
        x4.x = (x4.x - mean) * rstd; x4.y = (x4.y - mean) * rstd;
        x4.z = (x4.z - mean) * rstd; x4.w = (x4.w - mean) * rstd;
      }
      float xv[4] = {x4.x, x4.y, x4.z, x4.w};
      #pragma unroll
      for(int j = 0; j < 4; j++){
        int jj = (j + s4) & 3;  // rotate to spread LDS bank writes
        Bs[(s4 * 4 + jj) * LSTR + kr] = (f16)xv[jj];
      }
    }
    __syncthreads();
    f16x8 av[4], bv[4];
    #pragma unroll
    for(int mi = 0; mi < 4; mi++)
      av[mi] = *(const f16x8*)(As + (wm + mi * 16 + lr) * LSTR + lg * 8);
    #pragma unroll
    for(int ni = 0; ni < 4; ni++)
      bv[ni] = *(const f16x8*)(Bs + (wn + ni * 16 + lr) * LSTR + lg * 8);
    #pragma unroll
    for(int mi = 0; mi < 4; mi++){
      #pragma unroll
      for(int ni = 0; ni < 4; ni++)
        acc[mi][ni] = mfma16(av[mi], bv[ni], acc[mi][ni]);
    }
  }
  #pragma unroll
  for(int mi = 0; mi < 4; mi++){
    #pragma unroll
    for(int ni = 0; ni < 4; ni++){
      #pragma unroll
      for(int j = 0; j < 4; j++){
        int o = o0 + wm + mi * 16 + lg * 4 + j;
        int s = s0 + wn + ni * 16 + lr;
        Ob[(size_t)o * 4096 + s] = (f16)(acc[mi][ni][j] + bias[o]);
      }
    }
  }
}

// ============ 3. conv1x1 GEMM, fp16-split (hi/lo) 3-pass MFMA, f32 output ============
__global__ __launch_bounds__(256) void k_conv_hp(
    const float* __restrict__ X, const float* __restrict__ Wm,
    const float* __restrict__ bias, const float* __restrict__ stats,
    int norm_off, float* __restrict__ Out)
{
  const int b = blockIdx.z;
  const int o0 = blockIdx.y * 128;
  const int s0 = blockIdx.x * 128;
  const float* Xb = X + (size_t)b * 512 * 4096;
  float* Ob = Out + (size_t)b * 512 * 4096;
  __shared__ f16 Ah[128 * LSTR], Al[128 * LSTR], Bh[128 * LSTR], Bl[128 * LSTR];
  const int t = threadIdx.x;
  const int lane = t & 63, wid = t >> 6;
  const int wm = (wid >> 1) * 64, wn = (wid & 1) * 64;
  const int lr = lane & 15, lg = lane >> 4;
  f32x4 acc[4][4] = {};
  for(int kk = 0; kk < 512; kk += 32){
    __syncthreads();
    #pragma unroll
    for(int rep = 0; rep < 4; rep++){
      int q = t + 256 * rep;
      int row = q >> 3, c4 = q & 7;
      float4 w4 = *(const float4*)(Wm + (size_t)(o0 + row) * 512 + kk + c4 * 4);
      float wv[4] = {w4.x, w4.y, w4.z, w4.w};
      #pragma unroll
      for(int j = 0; j < 4; j++){
        f16 h = (f16)wv[j];
        f16 lo = (f16)(wv[j] - (float)h);
        Ah[row * LSTR + c4 * 4 + j] = h;
        Al[row * LSTR + c4 * 4 + j] = lo;
      }
    }
    #pragma unroll
    for(int rep = 0; rep < 4; rep++){
      int q = t + 256 * rep;
      int kr = q >> 5, s4 = q & 31;
      int c = kk + kr;
      float4 x4 = *(const float4*)(Xb + (size_t)c * 4096 + s0 + s4 * 4);
      if(norm_off >= 0){
        float mean = stats[norm_off + b * 512 + c];
        float rstd = stats[norm_off + 2048 + b * 512 + c];
        x4.x = (x4.x - mean) * rstd; x4.y = (x4.y - mean) * rstd;
        x4.z = (x4.z - mean) * rstd; x4.w = (x4.w - mean) * rstd;
      }
      float xv[4] = {x4.x, x4.y, x4.z, x4.w};
      #pragma unroll
      for(int j = 0; j < 4; j++){
        int jj = (j + s4) & 3;
        f16 h = (f16)xv[jj];
        f16 lo = (f16)(xv[jj] - (float)h);
        Bh[(s4 * 4 + jj) * LSTR + kr] = h;
        Bl[(s4 * 4 + jj) * LSTR + kr] = lo;
      }
    }
    __syncthreads();
    f16x8 ah[4], alo[4], bh[4], blo[4];
    #pragma unroll
    for(int mi = 0; mi < 4; mi++){
      ah[mi]  = *(const f16x8*)(Ah + (wm + mi * 16 + lr) * LSTR + lg * 8);
      alo[mi] = *(const f16x8*)(Al + (wm + mi * 16 + lr) * LSTR + lg * 8);
    }
    #pragma unroll
    for(int ni = 0; ni < 4; ni++){
      bh[ni]  = *(const f16x8*)(Bh + (wn + ni * 16 + lr) * LSTR + lg * 8);
      blo[ni] = *(const f16x8*)(Bl + (wn + ni * 16 + lr) * LSTR + lg * 8);
    }
    #pragma unroll
    for(int mi = 0; mi < 4; mi++){
      #pragma unroll
      for(int ni = 0; ni < 4; ni++){
        f32x4 a = acc[mi][ni];
        a = mfma16(ah[mi],  bh[ni],  a);
        a = mfma16(ah[mi],  blo[ni], a);
        a = mfma16(alo[mi], bh[ni],  a);
        acc[mi][ni] = a;
      }
    }
  }
  #pragma unroll
  for(int mi = 0; mi < 4; mi++){
    #pragma unroll
    for(int ni = 0; ni < 4; ni++){
      #pragma unroll
      for(int j = 0; j < 4; j++){
        int o = o0 + wm + mi * 16 + lg * 4 + j;
        int s = s0 + wn + ni * 16 + lr;
        Ob[(size_t)o * 4096 + s] = acc[mi][ni][j] + bias[o];
      }
    }
  }
}

// ============ 4. DA aggregation: k_c, sim=sigmoid(b+a*dis), k/v_agg ============
__global__ __launch_bounds__(256) void k_da1(
    const f16* __restrict__ K, const f16* __restrict__ V,
    const float* __restrict__ alpha_p, const float* __restrict__ beta_p,
    float* __restrict__ kagg, float* __restrict__ vagg)
{
  const int x = blockIdx.x & 63, bh = blockIdx.x >> 6;
  const f16* Kb = K + (size_t)bh * 64 * 4096;
  const f16* Vb = V + (size_t)bh * 64 * 4096;
  __shared__ float kl[64][65];
  __shared__ float vl[64][65];
  __shared__ float kc[64], vc[64], simv[64];
  const int t = threadIdx.x;
  const int c = t >> 2, yp = t & 3;
  const int xb = (x >> 3) * 512 + (x & 7) * 8;
  #pragma unroll
  for(int u = 0; u < 2; u++){
    int yh = yp * 2 + u;
    f16x8 k8 = *(const f16x8*)(Kb + (size_t)c * 4096 + xb + yh * 64);
    f16x8 v8 = *(const f16x8*)(Vb + (size_t)c * 4096 + xb + yh * 64);
    #pragma unroll
    for(int j = 0; j < 8; j++){
      kl[c][yh * 8 + j] = (float)k8[j];
      vl[c][yh * 8 + j] = (float)v8[j];
    }
  }
  __syncthreads();
  float sk = 0.f, sv = 0.f;
  for(int yy = yp * 16; yy < yp * 16 + 16; yy++){ sk += kl[c][yy]; sv += vl[c][yy]; }
  sk += __shfl_xor(sk, 1); sk += __shfl_xor(sk, 2);
  sv += __shfl_xor(sv, 1); sv += __shfl_xor(sv, 2);
  if(yp == 0){ kc[c] = sk * (1.f / 64.f); vc[c] = sv * (1.f / 64.f); }
  __syncthreads();
  const int y = t >> 2, cp = t & 3;
  float d = 0.f;
  for(int cc = cp * 16; cc < cp * 16 + 16; cc++) d += kc[cc] * kl[cc][y];
  d += __shfl_xor(d, 1); d += __shfl_xor(d, 2);
  if(cp == 0) simv[y] = 1.f / (1.f + expf(-(beta_p[0] + alpha_p[0] * d)));
  __syncthreads();
  float ak = 0.f, av = 0.f;
  for(int yy = yp * 16; yy < yp * 16 + 16; yy++){
    float sm = simv[yy];
    ak += sm * kl[c][yy]; av += sm * vl[c][yy];
  }
  ak += __shfl_xor(ak, 1); ak += __shfl_xor(ak, 2);
  av += __shfl_xor(av, 1); av += __shfl_xor(av, 2);
  if(yp == 0){
    size_t o = ((size_t)bh * 64 + x) * 64 + c;
    kagg[o] = (ak + kc[c]) * (1.f / 65.f);
    vagg[o] = (av + vc[c]) * (1.f / 65.f);
  }
}

// ============ 5. DA attention: per-query softmax over 64 aggregated keys ============
__global__ __launch_bounds__(256) void k_da2(
    const f16* __restrict__ Q, const float* __restrict__ kagg,
    const float* __restrict__ vagg, f16* __restrict__ Out)
{
  const int bh = blockIdx.x >> 4;
  const int s = ((blockIdx.x & 15) << 8) + threadIdx.x;  // spatial position = query
  const f16* Qb = Q + (size_t)bh * 64 * 4096;
  f16* Ob = Out + (size_t)bh * 64 * 4096;
  __shared__ float kz[4096];  // [z][c]
  __shared__ float vz[4096];
  const int t = threadIdx.x;
  #pragma unroll
  for(int rep = 0; rep < 4; rep++){
    int o = (t + rep * 256) * 4;
    *(float4*)(kz + o) = *(const float4*)(kagg + (size_t)bh * 4096 + o);
    *(float4*)(vz + o) = *(const float4*)(vagg + (size_t)bh * 4096 + o);
  }
  __syncthreads();
  float lg[64];
  #pragma unroll
  for(int z = 0; z < 64; z++) lg[z] = 0.f;
  for(int c = 0; c < 64; c++){
    float qv = (float)Qb[(size_t)c * 4096 + s];
    #pragma unroll
    for(int z = 0; z < 64; z++) lg[z] += qv * kz[z * 64 + c];
  }
  float m = lg[0];
  #pragma unroll
  for(int z = 1; z < 64; z++) m = fmaxf(m, lg[z]);
  float sum = 0.f;
  #pragma unroll
  for(int z = 0; z < 64; z++){ lg[z] = expf(lg[z] - m); sum += lg[z]; }
  float inv = 1.f / sum;
  for(int c = 0; c < 64; c++){
    float a = 0.f;
    #pragma unroll
    for(int z = 0; z < 64; z++) a += lg[z] * vz[z * 64 + c];
    Ob[(size_t)c * 4096 + s] = (f16)(a * inv);
  }
}

// ============ 6. PA1 + argmax (f32, precision-critical) ============
__global__ __launch_bounds__(256) void k_pa1(
    const float* __restrict__ Q2, const float* __restrict__ K2, int* __restrict__ idx)
{
  const int xp = blockIdx.x & 31;  // pair of x blocks
  const int bh = blockIdx.x >> 5;
  const float* Qb = Q2 + (size_t)bh * 64 * 4096;
  const float* Kb = K2 + (size_t)bh * 64 * 4096;
  __shared__ float ql[2][64][65];
  __shared__ float pa1[2][64];
  const int t = threadIdx.x;
  {
    const int c = t >> 2, q4 = t & 3;
    #pragma unroll
    for(int xi = 0; xi < 2; xi++){
      int x = xp * 2 + xi;
      int xb = (x >> 3) * 512 + (x & 7) * 8;
      #pragma unroll
      for(int u = 0; u < 4; u++){
        int y0 = (q4 * 4 + u) * 4;
        float4 v = *(const float4*)(Qb + (size_t)c * 4096 + xb + (y0 >> 3) * 64 + (y0 & 7));
        ql[xi][c][y0 + 0] = v.x; ql[xi][c][y0 + 1] = v.y;
        ql[xi][c][y0 + 2] = v.z; ql[xi][c][y0 + 3] = v.w;
      }
    }
  }
  __syncthreads();
  const int z = t >> 2, cp = t & 3;
  const int zb = (z >> 3) * 512 + (z & 7) * 8;
  float a0 = 0.f, a1 = 0.f;
  for(int c = cp * 16; c < cp * 16 + 16; c++){
    const float* kr = Kb + (size_t)c * 4096 + zb;
    #pragma unroll
    for(int yh = 0; yh < 8; yh++){
      float4 p = *(const float4*)(kr + yh * 64);
      float4 q = *(const float4*)(kr + yh * 64 + 4);
      int y0 = yh * 8;
      a0 += ql[0][c][y0+0]*p.x + ql[0][c][y0+1]*p.y + ql[0][c][y0+2]*p.z + ql[0][c][y0+3]*p.w
          + ql[0][c][y0+4]*q.x + ql[0][c][y0+5]*q.y + ql[0][c][y0+6]*q.z + ql[0][c][y0+7]*q.w;
      a1 += ql[1][c][y0+0]*p.x + ql[1][c][y0+1]*p.y + ql[1][c][y0+2]*p.z + ql[1][c][y0+3]*p.w
          + ql[1][c][y0+4]*q.x + ql[1][c][y0+5]*q.y + ql[1][c][y0+6]*q.z + ql[1][c][y0+7]*q.w;
    }
  }
  a0 += __shfl_xor(a0, 1); a0 += __shfl_xor(a0, 2);
  a1 += __shfl_xor(a1, 1); a1 += __shfl_xor(a1, 2);
  if(cp == 0){ pa1[0][z] = a0; pa1[1][z] = a1; }
  __syncthreads();
  if(t < 2){
    float best = pa1[t][0]; int bi = 0;
    for(int zz = 1; zz < 64; zz++){
      float v = pa1[t][zz];
      if(v > best){ best = v; bi = zz; }  // strict > keeps first occurrence (np.argmax)
    }
    idx[bh * 64 + xp * 2 + t] = bi;
  }
}

// ============ 7. PA intra-block attention ============
__global__ __launch_bounds__(256) void k_pa2(
    const float* __restrict__ Q2, const float* __restrict__ K2,
    const f16* __restrict__ V2, const int* __restrict__ idx, f16* __restrict__ Out)
{
  const int x = blockIdx.x & 63, bh = blockIdx.x >> 6;
  const float* Qb = Q2 + (size_t)bh * 64 * 4096;
  const float* Kb = K2 + (size_t)bh * 64 * 4096;
  const f16*  Vb = V2 + (size_t)bh * 64 * 4096;
  f16* Ob = Out + (size_t)bh * 64 * 4096;
  __shared__ float ql[64][65];
  __shared__ float kl[64][65];  // later reused as output staging [c][y]
  __shared__ float vl[64][65];
  __shared__ f16 pl[64][72];
  const int t = threadIdx.x;
  const int xk = idx[blockIdx.x];
  const int xb = (x >> 3) * 512 + (x & 7) * 8;
  const int kb = (xk >> 3) * 512 + (xk & 7) * 8;
  {
    const int c = t >> 2, q4 = t & 3;
    #pragma unroll
    for(int u = 0; u < 4; u++){
      int y0 = (q4 * 4 + u) * 4;
      int off = (y0 >> 3) * 64 + (y0 & 7);
      float4 a = *(const float4*)(Qb + (size_t)c * 4096 + xb + off);
      ql[c][y0+0] = a.x; ql[c][y0+1] = a.y; ql[c][y0+2] = a.z; ql[c][y0+3] = a.w;
      float4 bq = *(const float4*)(Kb + (size_t)c * 4096 + kb + off);
      kl[c][y0+0] = bq.x; kl[c][y0+1] = bq.y; kl[c][y0+2] = bq.z; kl[c][y0+3] = bq.w;
    }
    #pragma unroll
    for(int u = 0; u < 2; u++){
      int yh = (t & 3) * 2 + u;
      f16x8 v8 = *(const f16x8*)(Vb + (size_t)c * 4096 + kb + yh * 64);
      #pragma unroll
      for(int j = 0; j < 8; j++) vl[c][yh * 8 + j] = (float)v8[j];
    }
  }
  __syncthreads();
  const int y = t >> 2, zp = t & 3;
  float l[16];
  #pragma unroll
  for(int i = 0; i < 16; i++) l[i] = 0.f;
  for(int c = 0; c < 64; c++){
    float qv = ql[c][y];
    #pragma unroll
    for(int i = 0; i < 16; i++) l[i] += qv * kl[c][zp * 16 + i];
  }
  float m = l[0];
  #pragma unroll
  for(int i = 1; i < 16; i++) m = fmaxf(m, l[i]);
  m = fmaxf(m, __shfl_xor(m, 1)); m = fmaxf(m, __shfl_xor(m, 2));
  float sum = 0.f;
  #pragma unroll
  for(int i = 0; i < 16; i++){ l[i] = expf(l[i] - m); sum += l[i]; }
  sum += __shfl_xor(sum, 1); sum += __shfl_xor(sum, 2);
  float inv = 1.f / sum;
  #pragma unroll
  for(int i = 0; i < 16; i++) pl[y][zp * 16 + i] = (f16)(l[i] * inv);
  __syncthreads();  // all kl reads (logits) done; pl visible
  const int y2 = t >> 2, cp = t & 3;
  float ov[16];
  #pragma unroll
  for(int j = 0; j < 16; j++) ov[j] = 0.f;
  for(int z = 0; z < 64; z++){
    float pz = (float)pl[y2][z];
    #pragma unroll
    for(int j = 0; j < 16; j++) ov[j] += pz * vl[cp * 16 + j][z];
  }
  #pragma unroll
  for(int j = 0; j < 16; j++) kl[cp * 16 + j][y2] = ov[j];  // stage output [c][y]
  __syncthreads();
  {
    const int c = t >> 2, yp = t & 3;
    #pragma unroll
    for(int u = 0; u < 2; u++){
      int yh = yp * 2 + u;
      f16x8 w;
      #pragma unroll
      for(int j = 0; j < 8; j++) w[j] = (f16)kl[c][yh * 8 + j];
      *(f16x8*)(Ob + (size_t)c * 4096 + xb + yh * 64) = w;
    }
  }
}

// ============ 8. Fused output: f1*DA + f2*PA + biases + content -> f32 ============
__global__ __launch_bounds__(256) void k_final(
    const f16* __restrict__ X1, const float* __restrict__ W1, const float* __restrict__ B1,
    const f16* __restrict__ X2, const float* __restrict__ W2, const float* __restrict__ B2,
    const float* __restrict__ content, float* __restrict__ out)
{
  const int b = blockIdx.z;
  const int o0 = blockIdx.y * 128;
  const int s0 = blockIdx.x * 128;
  __shared__ f16 As[128 * LSTR];
  __shared__ f16 Bs[128 * LSTR];
  const int t = threadIdx.x;
  const int lane = t & 63, wid = t >> 6;
  const int wm = (wid >> 1) * 64, wn = (wid & 1) * 64;
  const int lr = lane & 15, lg = lane >> 4;
  f32x4 acc[4][4] = {};
  for(int pass = 0; pass < 2; pass++){
    const f16* Xb = (pass ? X2 : X1) + (size_t)b * 512 * 4096;
    const float* Wp = pass ? W2 : W1;
    for(int kk = 0; kk < 512; kk += 32){
      __syncthreads();
      #pragma unroll
      for(int rep = 0; rep < 4; rep++){
        int q = t + 256 * rep;
        int row = q >> 3, c4 = q & 7;
        float4 w4 = *(const float4*)(Wp + (size_t)(o0 + row) * 512 + kk + c4 * 4);
        f16* dst = As + row * LSTR + c4 * 4;
        dst[0] = (f16)w4.x; dst[1] = (f16)w4.y; dst[2] = (f16)w4.z; dst[3] = (f16)w4.w;
      }
      #pragma unroll
      for(int rep = 0; rep < 2; rep++){
        int q = t + 256 * rep;
        int kr = q >> 4, s8 = q & 15;
        f16x8 v = *(const f16x8*)(Xb + (size_t)(kk + kr) * 4096 + s0 + s8 * 8);
        #pragma unroll
        for(int j = 0; j < 8; j++){
          int jj = (j + s8) & 7;
          Bs[(s8 * 8 + jj) * LSTR + kr] = v[jj];
        }
      }
      __syncthreads();
      f16x8 av[4], bv[4];
      #pragma unroll
      for(int mi = 0; mi < 4; mi++)
        av[mi] = *(const f16x8*)(As + (wm + mi * 16 + lr) * LSTR + lg * 8);
      #pragma unroll
      for(int ni = 0; ni < 4; ni++)
        bv[ni] = *(const f16x8*)(Bs + (wn + ni * 16 + lr) * LSTR + lg * 8);
      #pragma unroll
      for(int mi = 0; mi < 4; mi++){
        #pragma unroll
        for(int ni = 0; ni < 4; ni++)
          acc[mi][ni] = mfma16(av[mi], bv[ni], acc[mi][ni]);
      }
    }
  }
  #pragma unroll
  for(int mi = 0; mi < 4; mi++){
    #pragma unroll
    for(int ni = 0; ni < 4; ni++){
      #pragma unroll
      for(int j = 0; j < 4; j++){
        int o = o0 + wm + mi * 16 + lg * 4 + j;
        int s = s0 + wn + ni * 16 + lr;
        size_t gi = ((size_t)b * 512 + o) * 4096 + s;
        out[gi] = acc[mi][ni][j] + B1[o] + B2[o] + content[gi];
      }
    }
  }
}

extern "C" void kernel_launch(void* const* d_in, const int* in_sizes, int n_in,
                              void* d_out, int out_size, void* d_ws, size_t ws_size,
                              hipStream_t stream) {
  (void)in_sizes; (void)n_in; (void)out_size; (void)ws_size;
  const float* content = (const float*)d_in[0];
  const float* style   = (const float*)d_in[1];
  const float* q_w  = (const float*)d_in[2];  const float* q_b  = (const float*)d_in[3];
  const float* k_w  = (const float*)d_in[4];  const float* k_b  = (const float*)d_in[5];
  const float* v_w  = (const float*)d_in[6];  const float* v_b  = (const float*)d_in[7];
  const float* q2_w = (const float*)d_in[8];  const float* q2_b = (const float*)d_in[9];
  const float* k2_w = (const float*)d_in[10]; const float* k2_b = (const float*)d_in[11];
  const float* v2_w = (const float*)d_in[12]; const float* v2_b = (const float*)d_in[13];
  const float* f1_w = (const float*)d_in[14]; const float* f1_b = (const float*)d_in[15];
  const float* f2_w = (const float*)d_in[16]; const float* f2_b = (const float*)d_in[17];
  const float* sim_alpha = (const float*)d_in[18];
  const float* sim_beta  = (const float*)d_in[19];

  char* ws = (char*)d_ws;
  float* q2buf = (float*)(ws + 0);                  // 33,554,432 B
  float* k2buf = (float*)(ws + 33554432);           // 33,554,432 B
  f16*   qbuf  = (f16*)(ws + 67108864);             // 16,777,216 B
  f16*   kbuf  = (f16*)(ws + 83886080);             // 16,777,216 B
  f16*   vbuf  = (f16*)(ws + 100663296);            // 16,777,216 B
  f16*   dabuf = (f16*)(ws + 117440512);            // 16,777,216 B
  f16*   v2buf = (f16*)(ws + 67108864);             // reuses qbuf slot (after da2)
  f16*   pabuf = (f16*)(ws + 83886080);             // reuses kbuf slot (after da1)
  float* stats = (float*)(ws + 134217728);          // 32,768 B
  float* kagg  = (float*)(ws + 134250496);          // 524,288 B
  float* vagg  = (float*)(ws + 134774784);          // 524,288 B
  int*   idxb  = (int*)(ws + 135299072);            // 8,192 B

  dim3 gconv(32, 4, 4);

  k_mvn_stats<<<4096, 256, 0, stream>>>(content, style, stats);

  // precision-critical path (feeds argmax): fp16-split, f32 outputs
  k_conv_hp<<<gconv, 256, 0, stream>>>(content, q2_w, q2_b, stats, 0,    q2buf);
  k_conv_hp<<<gconv, 256, 0, stream>>>(style,   k2_w, k2_b, stats, 4096, k2buf);

  // softmax-tolerant paths: plain fp16
  k_conv_h<<<gconv, 256, 0, stream>>>(content, q_w, q_b, stats, 0,    qbuf);
  k_conv_h<<<gconv, 256, 0, stream>>>(style,   k_w, k_b, stats, 4096, kbuf);
  k_conv_h<<<gconv, 256, 0, stream>>>(style,   v_w, v_b, stats, -1,   vbuf);

  k_da1<<<2048, 256, 0, stream>>>(kbuf, vbuf, sim_alpha, sim_beta, kagg, vagg);
  k_da2<<<512, 256, 0, stream>>>(qbuf, kagg, vagg, dabuf);

  k_conv_h<<<gconv, 256, 0, stream>>>(style, v2_w, v2_b, stats, -1, v2buf); // after da2 (reuses q slot)

  k_pa1<<<1024, 256, 0, stream>>>(q2buf, k2buf, idxb);
  k_pa2<<<2048, 256, 0, stream>>>(q2buf, k2buf, v2buf, idxb, pabuf);

  k_final<<<gconv, 256, 0, stream>>>(dabuf, f1_w, f1_b, pabuf, f2_w, f2_b,
                                     content, (float*)d_out);
}

// Round 2
// 648.241 us; speedup vs baseline: 1.1450x; 1.1450x over previous
//
#include <hip/hip_runtime.h>

typedef unsigned short u16;
typedef unsigned int   u32;
typedef _Float16       f16;

typedef f16   f16x8 __attribute__((ext_vector_type(8)));
typedef float f32x4 __attribute__((ext_vector_type(4)));

#define LSTR 40  // LDS row stride (elements) for 128x32 conv tiles; 40*2B=80B keeps 16B alignment

__device__ __forceinline__ f32x4 mfma16(f16x8 a, f16x8 b, f32x4 c){
  return __builtin_amdgcn_mfma_f32_16x16x32_f16(a, b, c, 0, 0, 0);
}

// ============ 1. per-(b,c) spatial mean / rstd for content & style ============
__global__ __launch_bounds__(256) void k_mvn_stats(
    const float* __restrict__ content, const float* __restrict__ style,
    float* __restrict__ stats)
{
  const int src = blockIdx.x >> 11;     // 0=content, 1=style
  const int row = blockIdx.x & 2047;    // b*512 + c
  const float* xp = (src ? style : content) + (size_t)row * 4096;
  const int t = threadIdx.x;
  double s = 0.0, ss = 0.0;
  for(int i = t * 4; i < 4096; i += 1024){
    float4 v = *(const float4*)(xp + i);
    s  += (double)v.x + (double)v.y + (double)v.z + (double)v.w;
    ss += (double)v.x * v.x + (double)v.y * v.y + (double)v.z * v.z + (double)v.w * v.w;
  }
  #pragma unroll
  for(int off = 32; off > 0; off >>= 1){
    s  += __shfl_xor(s, off);
    ss += __shfl_xor(ss, off);
  }
  __shared__ double sh[8];
  const int wid = t >> 6;
  if((t & 63) == 0){ sh[wid] = s; sh[4 + wid] = ss; }
  __syncthreads();
  if(t == 0){
    double S  = sh[0] + sh[1] + sh[2] + sh[3];
    double SS = sh[4] + sh[5] + sh[6] + sh[7];
    float mean = (float)(S * (1.0 / 4096.0));
    float var  = (float)((SS - S * S * (1.0 / 4096.0)) * (1.0 / 4095.0)); // ddof=1
    stats[src * 4096 + row] = mean;
    stats[src * 4096 + 2048 + row] = rsqrtf(var + 1e-5f);
  }
}

// ============ 2. conv1x1 GEMM, fp16 MFMA single-pass, fp16 output ============
__global__ __launch_bounds__(256) void k_conv_h(
    const float* __restrict__ X, const float* __restrict__ Wm,
    const float* __restrict__ bias, const float* __restrict__ stats,
    int norm_off, f16* __restrict__ Out)
{
  const int b = blockIdx.z;
  const int o0 = blockIdx.y * 128;
  const int s0 = blockIdx.x * 128;
  const float* Xb = X + (size_t)b * 512 * 4096;
  f16* Ob = Out + (size_t)b * 512 * 4096;
  __shared__ f16 As[128 * LSTR];
  __shared__ f16 Bs[128 * LSTR];
  const int t = threadIdx.x;
  const int lane = t & 63, wid = t >> 6;
  const int wm = (wid >> 1) * 64, wn = (wid & 1) * 64;
  const int lr = lane & 15, lg = lane >> 4;
  f32x4 acc[4][4] = {};
  for(int kk = 0; kk < 512; kk += 32){
    __syncthreads();
    #pragma unroll
    for(int rep = 0; rep < 4; rep++){
      int q = t + 256 * rep;
      int row = q >> 3, c4 = q & 7;
      float4 w4 = *(const float4*)(Wm + (size_t)(o0 + row) * 512 + kk + c4 * 4);
      f16* dst = As + row * LSTR + c4 * 4;
      dst[0] = (f16)w4.x; dst[1] = (f16)w4.y; dst[2] = (f16)w4.z; dst[3] = (f16)w4.w;
    }
    #pragma unroll
    for(int rep = 0; rep < 4; rep++){
      int q = t + 256 * rep;
      int kr = q >> 5, s4 = q & 31;
      int c = kk + kr;
      float4 x4 = *(const float4*)(Xb + (size_t)c * 4096 + s0 + s4 * 4);
      if(norm_off >= 0){
        float mean = stats[norm_off + b * 512 + c];
        float rstd = stats[norm_off + 2048 + b * 512 + c];
        x4.x = (x4.x - mean) * rstd; x4.y = (x4.y - mean) * rstd;
        x4.z = (x4.z - mean) * rstd; x4.w = (x4.w - mean) * rstd;
      }
      float xv[4] = {x4.x, x4.y, x4.z, x4.w};
      #pragma unroll
      for(int j = 0; j < 4; j++){
        int jj = (j + s4) & 3;
        Bs[(s4 * 4 + jj) * LSTR + kr] = (f16)xv[jj];
      }
    }
    __syncthreads();
    f16x8 av[4], bv[4];
    #pragma unroll
    for(int mi = 0; mi < 4; mi++)
      av[mi] = *(const f16x8*)(As + (wm + mi * 16 + lr) * LSTR + lg * 8);
    #pragma unroll
    for(int ni = 0; ni < 4; ni++)
      bv[ni] = *(const f16x8*)(Bs + (wn + ni * 16 + lr) * LSTR + lg * 8);
    #pragma unroll
    for(int mi = 0; mi < 4; mi++){
      #pragma unroll
      for(int ni = 0; ni < 4; ni++)
        acc[mi][ni] = mfma16(av[mi], bv[ni], acc[mi][ni]);
    }
  }
  #pragma unroll
  for(int mi = 0; mi < 4; mi++){
    #pragma unroll
    for(int ni = 0; ni < 4; ni++){
      #pragma unroll
      for(int j = 0; j < 4; j++){
        int o = o0 + wm + mi * 16 + lg * 4 + j;
        int s = s0 + wn + ni * 16 + lr;
        Ob[(size_t)o * 4096 + s] = (f16)(acc[mi][ni][j] + bias[o]);
      }
    }
  }
}

// ============ 3. conv1x1 GEMM, fp16-split (hi/lo) 3-pass MFMA, hi/lo f16 output ============
__global__ __launch_bounds__(256) void k_conv_hp(
    const float* __restrict__ X, const float* __restrict__ Wm,
    const float* __restrict__ bias, const float* __restrict__ stats,
    int norm_off, f16* __restrict__ Oh, f16* __restrict__ Ol)
{
  const int b = blockIdx.z;
  const int o0 = blockIdx.y * 128;
  const int s0 = blockIdx.x * 128;
  const float* Xb = X + (size_t)b * 512 * 4096;
  f16* Ohb = Oh + (size_t)b * 512 * 4096;
  f16* Olb = Ol + (size_t)b * 512 * 4096;
  __shared__ f16 Ah[128 * LSTR], Al[128 * LSTR], Bh[128 * LSTR], Bl[128 * LSTR];
  const int t = threadIdx.x;
  const int lane = t & 63, wid = t >> 6;
  const int wm = (wid >> 1) * 64, wn = (wid & 1) * 64;
  const int lr = lane & 15, lg = lane >> 4;
  f32x4 acc[4][4] = {};
  for(int kk = 0; kk < 512; kk += 32){
    __syncthreads();
    #pragma unroll
    for(int rep = 0; rep < 4; rep++){
      int q = t + 256 * rep;
      int row = q >> 3, c4 = q & 7;
      float4 w4 = *(const float4*)(Wm + (size_t)(o0 + row) * 512 + kk + c4 * 4);
      float wv[4] = {w4.x, w4.y, w4.z, w4.w};
      #pragma unroll
      for(int j = 0; j < 4; j++){
        f16 h = (f16)wv[j];
        f16 lo = (f16)(wv[j] - (float)h);
        Ah[row * LSTR + c4 * 4 + j] = h;
        Al[row * LSTR + c4 * 4 + j] = lo;
      }
    }
    #pragma unroll
    for(int rep = 0; rep < 4; rep++){
      int q = t + 256 * rep;
      int kr = q >> 5, s4 = q & 31;
      int c = kk + kr;
      float4 x4 = *(const float4*)(Xb + (size_t)c * 4096 + s0 + s4 * 4);
      if(norm_off >= 0){
        float mean = stats[norm_off + b * 512 + c];
        float rstd = stats[norm_off + 2048 + b * 512 + c];
        x4.x = (x4.x - mean) * rstd; x4.y = (x4.y - mean) * rstd;
        x4.z = (x4.z - mean) * rstd; x4.w = (x4.w - mean) * rstd;
      }
      float xv[4] = {x4.x, x4.y, x4.z, x4.w};
      #pragma unroll
      for(int j = 0; j < 4; j++){
        int jj = (j + s4) & 3;
        f16 h = (f16)xv[jj];
        f16 lo = (f16)(xv[jj] - (float)h);
        Bh[(s4 * 4 + jj) * LSTR + kr] = h;
        Bl[(s4 * 4 + jj) * LSTR + kr] = lo;
      }
    }
    __syncthreads();
    f16x8 ah[4], alo[4], bh[4], blo[4];
    #pragma unroll
    for(int mi = 0; mi < 4; mi++){
      ah[mi]  = *(const f16x8*)(Ah + (wm + mi * 16 + lr) * LSTR + lg * 8);
      alo[mi] = *(const f16x8*)(Al + (wm + mi * 16 + lr) * LSTR + lg * 8);
    }
    #pragma unroll
    for(int ni = 0; ni < 4; ni++){
      bh[ni]  = *(const f16x8*)(Bh + (wn + ni * 16 + lr) * LSTR + lg * 8);
      blo[ni] = *(const f16x8*)(Bl + (wn + ni * 16 + lr) * LSTR + lg * 8);
    }
    #pragma unroll
    for(int mi = 0; mi < 4; mi++){
      #pragma unroll
      for(int ni = 0; ni < 4; ni++){
        f32x4 a = acc[mi][ni];
        a = mfma16(ah[mi],  bh[ni],  a);
        a = mfma16(ah[mi],  blo[ni], a);
        a = mfma16(alo[mi], bh[ni],  a);
        acc[mi][ni] = a;
      }
    }
  }
  #pragma unroll
  for(int mi = 0; mi < 4; mi++){
    #pragma unroll
    for(int ni = 0; ni < 4; ni++){
      #pragma unroll
      for(int j = 0; j < 4; j++){
        int o = o0 + wm + mi * 16 + lg * 4 + j;
        int s = s0 + wn + ni * 16 + lr;
        float v = acc[mi][ni][j] + bias[o];
        f16 h = (f16)v;
        Ohb[(size_t)o * 4096 + s] = h;
        Olb[(size_t)o * 4096 + s] = (f16)(v - (float)h);
      }
    }
  }
}

// ============ 4. DA aggregation: k_c, sim=sigmoid(b+a*dis), k/v_agg ============
__global__ __launch_bounds__(256) void k_da1(
    const f16* __restrict__ K, const f16* __restrict__ V,
    const float* __restrict__ alpha_p, const float* __restrict__ beta_p,
    float* __restrict__ kagg, float* __restrict__ vagg)
{
  const int x = blockIdx.x & 63, bh = blockIdx.x >> 6;
  const f16* Kb = K + (size_t)bh * 64 * 4096;
  const f16* Vb = V + (size_t)bh * 64 * 4096;
  __shared__ float kl[64][65];
  __shared__ float vl[64][65];
  __shared__ float kc[64], vc[64], simv[64];
  const int t = threadIdx.x;
  const int c = t >> 2, yp = t & 3;
  const int xb = (x >> 3) * 512 + (x & 7) * 8;
  #pragma unroll
  for(int u = 0; u < 2; u++){
    int yh = yp * 2 + u;
    f16x8 k8 = *(const f16x8*)(Kb + (size_t)c * 4096 + xb + yh * 64);
    f16x8 v8 = *(const f16x8*)(Vb + (size_t)c * 4096 + xb + yh * 64);
    #pragma unroll
    for(int j = 0; j < 8; j++){
      kl[c][yh * 8 + j] = (float)k8[j];
      vl[c][yh * 8 + j] = (float)v8[j];
    }
  }
  __syncthreads();
  float sk = 0.f, sv = 0.f;
  for(int yy = yp * 16; yy < yp * 16 + 16; yy++){ sk += kl[c][yy]; sv += vl[c][yy]; }
  sk += __shfl_xor(sk, 1); sk += __shfl_xor(sk, 2);
  sv += __shfl_xor(sv, 1); sv += __shfl_xor(sv, 2);
  if(yp == 0){ kc[c] = sk * (1.f / 64.f); vc[c] = sv * (1.f / 64.f); }
  __syncthreads();
  const int y = t >> 2, cp = t & 3;
  float d = 0.f;
  for(int cc = cp * 16; cc < cp * 16 + 16; cc++) d += kc[cc] * kl[cc][y];
  d += __shfl_xor(d, 1); d += __shfl_xor(d, 2);
  if(cp == 0) simv[y] = 1.f / (1.f + expf(-(beta_p[0] + alpha_p[0] * d)));
  __syncthreads();
  float ak = 0.f, av = 0.f;
  for(int yy = yp * 16; yy < yp * 16 + 16; yy++){
    float sm = simv[yy];
    ak += sm * kl[c][yy]; av += sm * vl[c][yy];
  }
  ak += __shfl_xor(ak, 1); ak += __shfl_xor(ak, 2);
  av += __shfl_xor(av, 1); av += __shfl_xor(av, 2);
  if(yp == 0){
    size_t o = ((size_t)bh * 64 + x) * 64 + c;
    kagg[o] = (ak + kc[c]) * (1.f / 65.f);
    vagg[o] = (av + vc[c]) * (1.f / 65.f);
  }
}

// ============ 5. DA attention: per-query softmax over 64 aggregated keys ============
__global__ __launch_bounds__(256) void k_da2(
    const f16* __restrict__ Q, const float* __restrict__ kagg,
    const float* __restrict__ vagg, f16* __restrict__ Out)
{
  const int bh = blockIdx.x >> 4;
  const int s = ((blockIdx.x & 15) << 8) + threadIdx.x;
  const f16* Qb = Q + (size_t)bh * 64 * 4096;
  f16* Ob = Out + (size_t)bh * 64 * 4096;
  __shared__ float kz[4096];
  __shared__ float vz[4096];
  const int t = threadIdx.x;
  #pragma unroll
  for(int rep = 0; rep < 4; rep++){
    int o = (t + rep * 256) * 4;
    *(float4*)(kz + o) = *(const float4*)(kagg + (size_t)bh * 4096 + o);
    *(float4*)(vz + o) = *(const float4*)(vagg + (size_t)bh * 4096 + o);
  }
  __syncthreads();
  float lg[64];
  #pragma unroll
  for(int z = 0; z < 64; z++) lg[z] = 0.f;
  for(int c = 0; c < 64; c++){
    float qv = (float)Qb[(size_t)c * 4096 + s];
    #pragma unroll
    for(int z = 0; z < 64; z++) lg[z] += qv * kz[z * 64 + c];
  }
  float m = lg[0];
  #pragma unroll
  for(int z = 1; z < 64; z++) m = fmaxf(m, lg[z]);
  float sum = 0.f;
  #pragma unroll
  for(int z = 0; z < 64; z++){ lg[z] = expf(lg[z] - m); sum += lg[z]; }
  float inv = 1.f / sum;
  for(int c = 0; c < 64; c++){
    float a = 0.f;
    #pragma unroll
    for(int z = 0; z < 64; z++) a += lg[z] * vz[z * 64 + c];
    Ob[(size_t)c * 4096 + s] = (f16)(a * inv);
  }
}

// ============ 6. PA1 as split-K MFMA GEMM: PA1[x,z] = sum_{c,y} Q[c,x,y]K[c,z,y] ============
// grid: 32 bh x 8 c-slices. Each block: 64x64 output partial over 8 channels.
__global__ __launch_bounds__(256) void k_pa1(
    const f16* __restrict__ Qh, const f16* __restrict__ Ql,
    const f16* __restrict__ Kh, const f16* __restrict__ Kl,
    float* __restrict__ pa1p)
{
  const int slice = blockIdx.x & 7;
  const int bh = blockIdx.x >> 3;
  const size_t base = (size_t)bh * 64 * 4096;
  __shared__ f16 Ah[2][64][72], Al[2][64][72], Bh[2][64][72], Bl[2][64][72];
  const int t = threadIdx.x;
  const int lane = t & 63, wid = t >> 6;
  const int wm = (wid >> 1) * 32, wn = (wid & 1) * 32;
  const int lr = lane & 15, lg = lane >> 4;
  f32x4 acc[2][2] = {};
  for(int chunk = 0; chunk < 4; chunk++){
    const int c0 = slice * 8 + chunk * 2;
    __syncthreads();
    #pragma unroll
    for(int cc = 0; cc < 2; cc++){
      size_t cbase = base + (size_t)(c0 + cc) * 4096;
      #pragma unroll
      for(int u = 0; u < 2; u++){
        int e = u * 256 + t;
        int x = e >> 3, yh = e & 7;
        size_t src = cbase + (size_t)((x >> 3) * 512 + (x & 7) * 8 + yh * 64);
        int dst = yh * 8;
        *(f16x8*)(&Ah[cc][x][dst]) = *(const f16x8*)(Qh + src);
        *(f16x8*)(&Al[cc][x][dst]) = *(const f16x8*)(Ql + src);
        *(f16x8*)(&Bh[cc][x][dst]) = *(const f16x8*)(Kh + src);
        *(f16x8*)(&Bl[cc][x][dst]) = *(const f16x8*)(Kl + src);
      }
    }
    __syncthreads();
    #pragma unroll
    for(int cc = 0; cc < 2; cc++){
      #pragma unroll
      for(int kc = 0; kc < 2; kc++){
        f16x8 ah[2], alo[2], bh[2], blo[2];
        #pragma unroll
        for(int mi = 0; mi < 2; mi++){
          ah[mi]  = *(const f16x8*)(&Ah[cc][wm + mi * 16 + lr][kc * 32 + lg * 8]);
          alo[mi] = *(const f16x8*)(&Al[cc][wm + mi * 16 + lr][kc * 32 + lg * 8]);
        }
        #pragma unroll
        for(int ni = 0; ni < 2; ni++){
          bh[ni]  = *(const f16x8*)(&Bh[cc][wn + ni * 16 + lr][kc * 32 + lg * 8]);
          blo[ni] = *(const f16x8*)(&Bl[cc][wn + ni * 16 + lr][kc * 32 + lg * 8]);
        }
        #pragma unroll
        for(int mi = 0; mi < 2; mi++){
          #pragma unroll
          for(int ni = 0; ni < 2; ni++){
            f32x4 a = acc[mi][ni];
            a = mfma16(ah[mi],  bh[ni],  a);
            a = mfma16(ah[mi],  blo[ni], a);
            a = mfma16(alo[mi], bh[ni],  a);
            acc[mi][ni] = a;
          }
        }
      }
    }
  }
  float* outp = pa1p + ((size_t)bh * 8 + slice) * 4096;
  #pragma unroll
  for(int mi = 0; mi < 2; mi++){
    #pragma unroll
    for(int ni = 0; ni < 2; ni++){
      #pragma unroll
      for(int j = 0; j < 4; j++){
        int x = wm + mi * 16 + lg * 4 + j;
        int z = wn + ni * 16 + lr;
        outp[x * 64 + z] = acc[mi][ni][j];
      }
    }
  }
}

// ============ 6b. reduce partials + argmax (first max, np semantics) ============
__global__ __launch_bounds__(64) void k_pa1r(
    const float* __restrict__ pa1p, int* __restrict__ idx)
{
  const int bh = blockIdx.x;
  const int x = threadIdx.x;
  const float* p = pa1p + (size_t)bh * 8 * 4096 + x * 64;
  float best = -1e30f; int bi = 0;
  for(int z = 0; z < 64; z += 4){
    float4 v = *(const float4*)(p + z);
    #pragma unroll
    for(int sl = 1; sl < 8; sl++){
      float4 w = *(const float4*)(p + sl * 4096 + z);
      v.x += w.x; v.y += w.y; v.z += w.z; v.w += w.w;
    }
    if(v.x > best){ best = v.x; bi = z; }
    if(v.y > best){ best = v.y; bi = z + 1; }
    if(v.z > best){ best = v.z; bi = z + 2; }
    if(v.w > best){ best = v.w; bi = z + 3; }
  }
  idx[bh * 64 + x] = bi;
}

// ============ 7. PA intra-block attention ============
__global__ __launch_bounds__(256) void k_pa2(
    const f16* __restrict__ Qh, const f16* __restrict__ Ql2,
    const f16* __restrict__ Kh, const f16* __restrict__ Kl2,
    const f16* __restrict__ V2, const int* __restrict__ idx, f16* __restrict__ Out)
{
  const int x = blockIdx.x & 63, bh = blockIdx.x >> 6;
  const size_t base = (size_t)bh * 64 * 4096;
  f16* Ob = Out + base;
  __shared__ float ql[64][65];
  __shared__ float kl[64][65];  // later reused as output staging [c][y]
  __shared__ float vl[64][65];
  __shared__ f16 pl[64][72];
  const int t = threadIdx.x;
  const int xk = idx[blockIdx.x];
  const int xb = (x >> 3) * 512 + (x & 7) * 8;
  const int kb = (xk >> 3) * 512 + (xk & 7) * 8;
  {
    const int c = t >> 2, q4 = t & 3;
    #pragma unroll
    for(int u = 0; u < 2; u++){
      int yh = q4 * 2 + u;
      size_t offq = base + (size_t)c * 4096 + xb + yh * 64;
      size_t offk = base + (size_t)c * 4096 + kb + yh * 64;
      f16x8 qh8 = *(const f16x8*)(Qh + offq);
      f16x8 ql8 = *(const f16x8*)(Ql2 + offq);
      f16x8 kh8 = *(const f16x8*)(Kh + offk);
      f16x8 kl8 = *(const f16x8*)(Kl2 + offk);
      f16x8 vh8 = *(const f16x8*)(V2 + offk);
      #pragma unroll
      for(int j = 0; j < 8; j++){
        ql[c][yh * 8 + j] = (float)qh8[j] + (float)ql8[j];
        kl[c][yh * 8 + j] = (float)kh8[j] + (float)kl8[j];
        vl[c][yh * 8 + j] = (float)vh8[j];
      }
    }
  }
  __syncthreads();
  const int y = t >> 2, zp = t & 3;
  float l[16];
  #pragma unroll
  for(int i = 0; i < 16; i++) l[i] = 0.f;
  for(int c = 0; c < 64; c++){
    float qv = ql[c][y];
    #pragma unroll
    for(int i = 0; i < 16; i++) l[i] += qv * kl[c][zp * 16 + i];
  }
  float m = l[0];
  #pragma unroll
  for(int i = 1; i < 16; i++) m = fmaxf(m, l[i]);
  m = fmaxf(m, __shfl_xor(m, 1)); m = fmaxf(m, __shfl_xor(m, 2));
  float sum = 0.f;
  #pragma unroll
  for(int i = 0; i < 16; i++){ l[i] = expf(l[i] - m); sum += l[i]; }
  sum += __shfl_xor(sum, 1); sum += __shfl_xor(sum, 2);
  float inv = 1.f / sum;
  #pragma unroll
  for(int i = 0; i < 16; i++) pl[y][zp * 16 + i] = (f16)(l[i] * inv);
  __syncthreads();
  const int y2 = t >> 2, cp = t & 3;
  float ov[16];
  #pragma unroll
  for(int j = 0; j < 16; j++) ov[j] = 0.f;
  for(int z = 0; z < 64; z++){
    float pz = (float)pl[y2][z];
    #pragma unroll
    for(int j = 0; j < 16; j++) ov[j] += pz * vl[cp * 16 + j][z];
  }
  #pragma unroll
  for(int j = 0; j < 16; j++) kl[cp * 16 + j][y2] = ov[j];
  __syncthreads();
  {
    const int c = t >> 2, yp = t & 3;
    #pragma unroll
    for(int u = 0; u < 2; u++){
      int yh = yp * 2 + u;
      f16x8 w;
      #pragma unroll
      for(int j = 0; j < 8; j++) w[j] = (f16)kl[c][yh * 8 + j];
      *(f16x8*)(Ob + (size_t)c * 4096 + xb + yh * 64) = w;
    }
  }
}

// ============ 8. Fused output: f1*DA + f2*PA + biases + content -> f32 ============
__global__ __launch_bounds__(256) void k_final(
    const f16* __restrict__ X1, const float* __restrict__ W1, const float* __restrict__ B1,
    const f16* __restrict__ X2, const float* __restrict__ W2, const float* __restrict__ B2,
    const float* __restrict__ content, float* __restrict__ out)
{
  const int b = blockIdx.z;
  const int o0 = blockIdx.y * 128;
  const int s0 = blockIdx.x * 128;
  __shared__ f16 As[128 * LSTR];
  __shared__ f16 Bs[128 * LSTR];
  const int t = threadIdx.x;
  const int lane = t & 63, wid = t >> 6;
  const int wm = (wid >> 1) * 64, wn = (wid & 1) * 64;
  const int lr = lane & 15, lg = lane >> 4;
  f32x4 acc[4][4] = {};
  for(int pass = 0; pass < 2; pass++){
    const f16* Xb = (pass ? X2 : X1) + (size_t)b * 512 * 4096;
    const float* Wp = pass ? W2 : W1;
    for(int kk = 0; kk < 512; kk += 32){
      __syncthreads();
      #pragma unroll
      for(int rep = 0; rep < 4; rep++){
        int q = t + 256 * rep;
        int row = q >> 3, c4 = q & 7;
        float4 w4 = *(const float4*)(Wp + (size_t)(o0 + row) * 512 + kk + c4 * 4);
        f16* dst = As + row * LSTR + c4 * 4;
        dst[0] = (f16)w4.x; dst[1] = (f16)w4.y; dst[2] = (f16)w4.z; dst[3] = (f16)w4.w;
      }
      #pragma unroll
      for(int rep = 0; rep < 2; rep++){
        int q = t + 256 * rep;
        int kr = q >> 4, s8 = q & 15;
        f16x8 v = *(const f16x8*)(Xb + (size_t)(kk + kr) * 4096 + s0 + s8 * 8);
        #pragma unroll
        for(int j = 0; j < 8; j++){
          int jj = (j + s8) & 7;
          Bs[(s8 * 8 + jj) * LSTR + kr] = v[jj];
        }
      }
      __syncthreads();
      f16x8 av[4], bv[4];
      #pragma unroll
      for(int mi = 0; mi < 4; mi++)
        av[mi] = *(const f16x8*)(As + (wm + mi * 16 + lr) * LSTR + lg * 8);
      #pragma unroll
      for(int ni = 0; ni < 4; ni++)
        bv[ni] = *(const f16x8*)(Bs + (wn + ni * 16 + lr) * LSTR + lg * 8);
      #pragma unroll
      for(int mi = 0; mi < 4; mi++){
        #pragma unroll
        for(int ni = 0; ni < 4; ni++)
          acc[mi][ni] = mfma16(av[mi], bv[ni], acc[mi][ni]);
      }
    }
  }
  #pragma unroll
  for(int mi = 0; mi < 4; mi++){
    #pragma unroll
    for(int ni = 0; ni < 4; ni++){
      #pragma unroll
      for(int j = 0; j < 4; j++){
        int o = o0 + wm + mi * 16 + lg * 4 + j;
        int s = s0 + wn + ni * 16 + lr;
        size_t gi = ((size_t)b * 512 + o) * 4096 + s;
        out[gi] = acc[mi][ni][j] + B1[o] + B2[o] + content[gi];
      }
    }
  }
}

extern "C" void kernel_launch(void* const* d_in, const int* in_sizes, int n_in,
                              void* d_out, int out_size, void* d_ws, size_t ws_size,
                              hipStream_t stream) {
  (void)in_sizes; (void)n_in; (void)out_size; (void)ws_size;
  const float* content = (const float*)d_in[0];
  const float* style   = (const float*)d_in[1];
  const float* q_w  = (const float*)d_in[2];  const float* q_b  = (const float*)d_in[3];
  const float* k_w  = (const float*)d_in[4];  const float* k_b  = (const float*)d_in[5];
  const float* v_w  = (const float*)d_in[6];  const float* v_b  = (const float*)d_in[7];
  const float* q2_w = (const float*)d_in[8];  const float* q2_b = (const float*)d_in[9];
  const float* k2_w = (const float*)d_in[10]; const float* k2_b = (const float*)d_in[11];
  const float* v2_w = (const float*)d_in[12]; const float* v2_b = (const float*)d_in[13];
  const float* f1_w = (const float*)d_in[14]; const float* f1_b = (const float*)d_in[15];
  const float* f2_w = (const float*)d_in[16]; const float* f2_b = (const float*)d_in[17];
  const float* sim_alpha = (const float*)d_in[18];
  const float* sim_beta  = (const float*)d_in[19];

  char* ws = (char*)d_ws;
  f16*   q2h  = (f16*)(ws + 0);                // 16,777,216 B
  f16*   q2l  = (f16*)(ws + 16777216);         // 16,777,216 B
  f16*   k2h  = (f16*)(ws + 33554432);         // 16,777,216 B
  f16*   k2l  = (f16*)(ws + 50331648);         // 16,777,216 B
  f16*   qbuf = (f16*)(ws + 67108864);         // 16,777,216 B
  f16*   kbuf = (f16*)(ws + 83886080);         // 16,777,216 B
  f16*   vbuf = (f16*)(ws + 100663296);        // 16,777,216 B
  f16*   dabuf= (f16*)(ws + 117440512);        // 16,777,216 B
  f16*   v2buf= (f16*)(ws + 67108864);         // reuses qbuf slot (after da2)
  f16*   pabuf= (f16*)(ws + 83886080);         // reuses kbuf slot (after da1)
  float* pa1p = (float*)(ws + 100663296);      // reuses vbuf slot (after da1), 4 MB
  float* stats= (float*)(ws + 134217728);      // 32,768 B
  float* kagg = (float*)(ws + 134250496);      // 524,288 B
  float* vagg = (float*)(ws + 134774784);      // 524,288 B
  int*   idxb = (int*)(ws + 135299072);        // 8,192 B

  dim3 gconv(32, 4, 4);

  k_mvn_stats<<<4096, 256, 0, stream>>>(content, style, stats);

  // precision-critical path (feeds argmax): fp16-split, hi/lo f16 outputs
  k_conv_hp<<<gconv, 256, 0, stream>>>(content, q2_w, q2_b, stats, 0,    q2h, q2l);
  k_conv_hp<<<gconv, 256, 0, stream>>>(style,   k2_w, k2_b, stats, 4096, k2h, k2l);

  // softmax-tolerant paths: plain fp16
  k_conv_h<<<gconv, 256, 0, stream>>>(content, q_w, q_b, stats, 0,    qbuf);
  k_conv_h<<<gconv, 256, 0, stream>>>(style,   k_w, k_b, stats, 4096, kbuf);
  k_conv_h<<<gconv, 256, 0, stream>>>(style,   v_w, v_b, stats, -1,   vbuf);

  k_da1<<<2048, 256, 0, stream>>>(kbuf, vbuf, sim_alpha, sim_beta, kagg, vagg);
  k_da2<<<512, 256, 0, stream>>>(qbuf, kagg, vagg, dabuf);

  k_conv_h<<<gconv, 256, 0, stream>>>(style, v2_w, v2_b, stats, -1, v2buf); // after da2 (reuses q slot)

  k_pa1<<<256, 256, 0, stream>>>(q2h, q2l, k2h, k2l, pa1p);   // after da1 (pa1p reuses v slot)
  k_pa1r<<<32, 64, 0, stream>>>(pa1p, idxb);
  k_pa2<<<2048, 256, 0, stream>>>(q2h, q2l, k2h, k2l, v2buf, idxb, pabuf);

  k_final<<<gconv, 256, 0, stream>>>(dabuf, f1_w, f1_b, pabuf, f2_w, f2_b,
                                     content, (float*)d_out);
}

// Round 3
// 645.944 us; speedup vs baseline: 1.1491x; 1.0036x over previous
//
#include <hip/hip_runtime.h>

typedef unsigned short u16;
typedef unsigned int   u32;
typedef _Float16       f16;

typedef f16   f16x8 __attribute__((ext_vector_type(8)));
typedef float f32x4 __attribute__((ext_vector_type(4)));

#define LSTR 40  // LDS row stride (elements) for 128x32 conv tiles; 40*2B=80B keeps 16B alignment

__device__ __forceinline__ f32x4 mfma16(f16x8 a, f16x8 b, f32x4 c){
  return __builtin_amdgcn_mfma_f32_16x16x32_f16(a, b, c, 0, 0, 0);
}

// ============ 1. per-(b,c) spatial mean / rstd for content & style ============
__global__ __launch_bounds__(256) void k_mvn_stats(
    const float* __restrict__ content, const float* __restrict__ style,
    float* __restrict__ stats)
{
  const int src = blockIdx.x >> 11;     // 0=content, 1=style
  const int row = blockIdx.x & 2047;    // b*512 + c
  const float* xp = (src ? style : content) + (size_t)row * 4096;
  const int t = threadIdx.x;
  double s = 0.0, ss = 0.0;
  for(int i = t * 4; i < 4096; i += 1024){
    float4 v = *(const float4*)(xp + i);
    s  += (double)v.x + (double)v.y + (double)v.z + (double)v.w;
    ss += (double)v.x * v.x + (double)v.y * v.y + (double)v.z * v.z + (double)v.w * v.w;
  }
  #pragma unroll
  for(int off = 32; off > 0; off >>= 1){
    s  += __shfl_xor(s, off);
    ss += __shfl_xor(ss, off);
  }
  __shared__ double sh[8];
  const int wid = t >> 6;
  if((t & 63) == 0){ sh[wid] = s; sh[4 + wid] = ss; }
  __syncthreads();
  if(t == 0){
    double S  = sh[0] + sh[1] + sh[2] + sh[3];
    double SS = sh[4] + sh[5] + sh[6] + sh[7];
    float mean = (float)(S * (1.0 / 4096.0));
    float var  = (float)((SS - S * S * (1.0 / 4096.0)) * (1.0 / 4095.0)); // ddof=1
    stats[src * 4096 + row] = mean;
    stats[src * 4096 + 2048 + row] = rsqrtf(var + 1e-5f);
  }
}

// ============ 2. conv1x1 GEMM, fp16 MFMA single-pass, fp16 output ============
__global__ __launch_bounds__(256) void k_conv_h(
    const float* __restrict__ X, const float* __restrict__ Wm,
    const float* __restrict__ bias, const float* __restrict__ stats,
    int norm_off, f16* __restrict__ Out)
{
  const int b = blockIdx.z;
  const int o0 = blockIdx.y * 128;
  const int s0 = blockIdx.x * 128;
  const float* Xb = X + (size_t)b * 512 * 4096;
  f16* Ob = Out + (size_t)b * 512 * 4096;
  __shared__ f16 As[128 * LSTR];
  __shared__ f16 Bs[128 * LSTR];
  const int t = threadIdx.x;
  const int lane = t & 63, wid = t >> 6;
  const int wm = (wid >> 1) * 64, wn = (wid & 1) * 64;
  const int lr = lane & 15, lg = lane >> 4;
  f32x4 acc[4][4] = {};
  for(int kk = 0; kk < 512; kk += 32){
    __syncthreads();
    #pragma unroll
    for(int rep = 0; rep < 4; rep++){
      int q = t + 256 * rep;
      int row = q >> 3, c4 = q & 7;
      float4 w4 = *(const float4*)(Wm + (size_t)(o0 + row) * 512 + kk + c4 * 4);
      f16* dst = As + row * LSTR + c4 * 4;
      dst[0] = (f16)w4.x; dst[1] = (f16)w4.y; dst[2] = (f16)w4.z; dst[3] = (f16)w4.w;
    }
    #pragma unroll
    for(int rep = 0; rep < 4; rep++){
      int q = t + 256 * rep;
      int kr = q >> 5, s4 = q & 31;
      int c = kk + kr;
      float4 x4 = *(const float4*)(Xb + (size_t)c * 4096 + s0 + s4 * 4);
      if(norm_off >= 0){
        float mean = stats[norm_off + b * 512 + c];
        float rstd = stats[norm_off + 2048 + b * 512 + c];
        x4.x = (x4.x - mean) * rstd; x4.y = (x4.y - mean) * rstd;
        x4.z = (x4.z - mean) * rstd; x4.w = (x4.w - mean) * rstd;
      }
      float xv[4] = {x4.x, x4.y, x4.z, x4.w};
      #pragma unroll
      for(int j = 0; j < 4; j++){
        int jj = (j + s4) & 3;
        Bs[(s4 * 4 + jj) * LSTR + kr] = (f16)xv[jj];
      }
    }
    __syncthreads();
    f16x8 av[4], bv[4];
    #pragma unroll
    for(int mi = 0; mi < 4; mi++)
      av[mi] = *(const f16x8*)(As + (wm + mi * 16 + lr) * LSTR + lg * 8);
    #pragma unroll
    for(int ni = 0; ni < 4; ni++)
      bv[ni] = *(const f16x8*)(Bs + (wn + ni * 16 + lr) * LSTR + lg * 8);
    #pragma unroll
    for(int mi = 0; mi < 4; mi++){
      #pragma unroll
      for(int ni = 0; ni < 4; ni++)
        acc[mi][ni] = mfma16(av[mi], bv[ni], acc[mi][ni]);
    }
  }
  #pragma unroll
  for(int mi = 0; mi < 4; mi++){
    #pragma unroll
    for(int ni = 0; ni < 4; ni++){
      #pragma unroll
      for(int j = 0; j < 4; j++){
        int o = o0 + wm + mi * 16 + lg * 4 + j;
        int s = s0 + wn + ni * 16 + lr;
        Ob[(size_t)o * 4096 + s] = (f16)(acc[mi][ni][j] + bias[o]);
      }
    }
  }
}

// ============ 3. conv1x1 GEMM, fp16-split (hi/lo) 3-pass MFMA, hi/lo f16 output ============
__global__ __launch_bounds__(256) void k_conv_hp(
    const float* __restrict__ X, const float* __restrict__ Wm,
    const float* __restrict__ bias, const float* __restrict__ stats,
    int norm_off, f16* __restrict__ Oh, f16* __restrict__ Ol)
{
  const int b = blockIdx.z;
  const int o0 = blockIdx.y * 128;
  const int s0 = blockIdx.x * 128;
  const float* Xb = X + (size_t)b * 512 * 4096;
  f16* Ohb = Oh + (size_t)b * 512 * 4096;
  f16* Olb = Ol + (size_t)b * 512 * 4096;
  __shared__ f16 Ah[128 * LSTR], Al[128 * LSTR], Bh[128 * LSTR], Bl[128 * LSTR];
  const int t = threadIdx.x;
  const int lane = t & 63, wid = t >> 6;
  const int wm = (wid >> 1) * 64, wn = (wid & 1) * 64;
  const int lr = lane & 15, lg = lane >> 4;
  f32x4 acc[4][4] = {};
  for(int kk = 0; kk < 512; kk += 32){
    __syncthreads();
    #pragma unroll
    for(int rep = 0; rep < 4; rep++){
      int q = t + 256 * rep;
      int row = q >> 3, c4 = q & 7;
      float4 w4 = *(const float4*)(Wm + (size_t)(o0 + row) * 512 + kk + c4 * 4);
      float wv[4] = {w4.x, w4.y, w4.z, w4.w};
      #pragma unroll
      for(int j = 0; j < 4; j++){
        f16 h = (f16)wv[j];
        f16 lo = (f16)(wv[j] - (float)h);
        Ah[row * LSTR + c4 * 4 + j] = h;
        Al[row * LSTR + c4 * 4 + j] = lo;
      }
    }
    #pragma unroll
    for(int rep = 0; rep < 4; rep++){
      int q = t + 256 * rep;
      int kr = q >> 5, s4 = q & 31;
      int c = kk + kr;
      float4 x4 = *(const float4*)(Xb + (size_t)c * 4096 + s0 + s4 * 4);
      if(norm_off >= 0){
        float mean = stats[norm_off + b * 512 + c];
        float rstd = stats[norm_off + 2048 + b * 512 + c];
        x4.x = (x4.x - mean) * rstd; x4.y = (x4.y - mean) * rstd;
        x4.z = (x4.z - mean) * rstd; x4.w = (x4.w - mean) * rstd;
      }
      float xv[4] = {x4.x, x4.y, x4.z, x4.w};
      #pragma unroll
      for(int j = 0; j < 4; j++){
        int jj = (j + s4) & 3;
        f16 h = (f16)xv[jj];
        f16 lo = (f16)(xv[jj] - (float)h);
        Bh[(s4 * 4 + jj) * LSTR + kr] = h;
        Bl[(s4 * 4 + jj) * LSTR + kr] = lo;
      }
    }
    __syncthreads();
    f16x8 ah[4], alo[4], bh[4], blo[4];
    #pragma unroll
    for(int mi = 0; mi < 4; mi++){
      ah[mi]  = *(const f16x8*)(Ah + (wm + mi * 16 + lr) * LSTR + lg * 8);
      alo[mi] = *(const f16x8*)(Al + (wm + mi * 16 + lr) * LSTR + lg * 8);
    }
    #pragma unroll
    for(int ni = 0; ni < 4; ni++){
      bh[ni]  = *(const f16x8*)(Bh + (wn + ni * 16 + lr) * LSTR + lg * 8);
      blo[ni] = *(const f16x8*)(Bl + (wn + ni * 16 + lr) * LSTR + lg * 8);
    }
    #pragma unroll
    for(int mi = 0; mi < 4; mi++){
      #pragma unroll
      for(int ni = 0; ni < 4; ni++){
        f32x4 a = acc[mi][ni];
        a = mfma16(ah[mi],  bh[ni],  a);
        a = mfma16(ah[mi],  blo[ni], a);
        a = mfma16(alo[mi], bh[ni],  a);
        acc[mi][ni] = a;
      }
    }
  }
  #pragma unroll
  for(int mi = 0; mi < 4; mi++){
    #pragma unroll
    for(int ni = 0; ni < 4; ni++){
      #pragma unroll
      for(int j = 0; j < 4; j++){
        int o = o0 + wm + mi * 16 + lg * 4 + j;
        int s = s0 + wn + ni * 16 + lr;
        float v = acc[mi][ni][j] + bias[o];
        f16 h = (f16)v;
        Ohb[(size_t)o * 4096 + s] = h;
        Olb[(size_t)o * 4096 + s] = (f16)(v - (float)h);
      }
    }
  }
}

// ============ 4. DA aggregation: k_c, sim=sigmoid(b+a*dis), k/v_agg ============
__global__ __launch_bounds__(256) void k_da1(
    const f16* __restrict__ K, const f16* __restrict__ V,
    const float* __restrict__ alpha_p, const float* __restrict__ beta_p,
    float* __restrict__ kagg, float* __restrict__ vagg)
{
  const int x = blockIdx.x & 63, bh = blockIdx.x >> 6;
  const f16* Kb = K + (size_t)bh * 64 * 4096;
  const f16* Vb = V + (size_t)bh * 64 * 4096;
  __shared__ float kl[64][65];
  __shared__ float vl[64][65];
  __shared__ float kc[64], vc[64], simv[64];
  const int t = threadIdx.x;
  const int c = t >> 2, yp = t & 3;
  const int xb = (x >> 3) * 512 + (x & 7) * 8;
  #pragma unroll
  for(int u = 0; u < 2; u++){
    int yh = yp * 2 + u;
    f16x8 k8 = *(const f16x8*)(Kb + (size_t)c * 4096 + xb + yh * 64);
    f16x8 v8 = *(const f16x8*)(Vb + (size_t)c * 4096 + xb + yh * 64);
    #pragma unroll
    for(int j = 0; j < 8; j++){
      kl[c][yh * 8 + j] = (float)k8[j];
      vl[c][yh * 8 + j] = (float)v8[j];
    }
  }
  __syncthreads();
  float sk = 0.f, sv = 0.f;
  for(int yy = yp * 16; yy < yp * 16 + 16; yy++){ sk += kl[c][yy]; sv += vl[c][yy]; }
  sk += __shfl_xor(sk, 1); sk += __shfl_xor(sk, 2);
  sv += __shfl_xor(sv, 1); sv += __shfl_xor(sv, 2);
  if(yp == 0){ kc[c] = sk * (1.f / 64.f); vc[c] = sv * (1.f / 64.f); }
  __syncthreads();
  const int y = t >> 2, cp = t & 3;
  float d = 0.f;
  for(int cc = cp * 16; cc < cp * 16 + 16; cc++) d += kc[cc] * kl[cc][y];
  d += __shfl_xor(d, 1); d += __shfl_xor(d, 2);
  if(cp == 0) simv[y] = 1.f / (1.f + expf(-(beta_p[0] + alpha_p[0] * d)));
  __syncthreads();
  float ak = 0.f, av = 0.f;
  for(int yy = yp * 16; yy < yp * 16 + 16; yy++){
    float sm = simv[yy];
    ak += sm * kl[c][yy]; av += sm * vl[c][yy];
  }
  ak += __shfl_xor(ak, 1); ak += __shfl_xor(ak, 2);
  av += __shfl_xor(av, 1); av += __shfl_xor(av, 2);
  if(yp == 0){
    size_t o = ((size_t)bh * 64 + x) * 64 + c;
    kagg[o] = (ak + kc[c]) * (1.f / 65.f);
    vagg[o] = (av + vc[c]) * (1.f / 65.f);
  }
}

// ============ 5. DA attention: per-query softmax over 64 aggregated keys ============
__global__ __launch_bounds__(256) void k_da2(
    const f16* __restrict__ Q, const float* __restrict__ kagg,
    const float* __restrict__ vagg, f16* __restrict__ Out)
{
  const int bh = blockIdx.x >> 4;
  const int s = ((blockIdx.x & 15) << 8) + threadIdx.x;
  const f16* Qb = Q + (size_t)bh * 64 * 4096;
  f16* Ob = Out + (size_t)bh * 64 * 4096;
  __shared__ float kz[4096];
  __shared__ float vz[4096];
  const int t = threadIdx.x;
  #pragma unroll
  for(int rep = 0; rep < 4; rep++){
    int o = (t + rep * 256) * 4;
    *(float4*)(kz + o) = *(const float4*)(kagg + (size_t)bh * 4096 + o);
    *(float4*)(vz + o) = *(const float4*)(vagg + (size_t)bh * 4096 + o);
  }
  __syncthreads();
  float lg[64];
  #pragma unroll
  for(int z = 0; z < 64; z++) lg[z] = 0.f;
  for(int c = 0; c < 64; c++){
    float qv = (float)Qb[(size_t)c * 4096 + s];
    #pragma unroll
    for(int z = 0; z < 64; z++) lg[z] += qv * kz[z * 64 + c];
  }
  float m = lg[0];
  #pragma unroll
  for(int z = 1; z < 64; z++) m = fmaxf(m, lg[z]);
  float sum = 0.f;
  #pragma unroll
  for(int z = 0; z < 64; z++){ lg[z] = expf(lg[z] - m); sum += lg[z]; }
  float inv = 1.f / sum;
  for(int c = 0; c < 64; c++){
    float a = 0.f;
    #pragma unroll
    for(int z = 0; z < 64; z++) a += lg[z] * vz[z * 64 + c];
    Ob[(size_t)c * 4096 + s] = (f16)(a * inv);
  }
}

// ============ 6. PA1 as split-K MFMA GEMM: PA1[x,z] = sum_{c,y} Q[c,x,y]K[c,z,y] ============
__global__ __launch_bounds__(256) void k_pa1(
    const f16* __restrict__ Qh, const f16* __restrict__ Ql,
    const f16* __restrict__ Kh, const f16* __restrict__ Kl,
    float* __restrict__ pa1p)
{
  const int slice = blockIdx.x & 7;
  const int bh = blockIdx.x >> 3;
  const size_t base = (size_t)bh * 64 * 4096;
  __shared__ f16 Ah[2][64][72], Al[2][64][72], Bh[2][64][72], Bl[2][64][72];
  const int t = threadIdx.x;
  const int lane = t & 63, wid = t >> 6;
  const int wm = (wid >> 1) * 32, wn = (wid & 1) * 32;
  const int lr = lane & 15, lg = lane >> 4;
  f32x4 acc[2][2] = {};
  for(int chunk = 0; chunk < 4; chunk++){
    const int c0 = slice * 8 + chunk * 2;
    __syncthreads();
    #pragma unroll
    for(int cc = 0; cc < 2; cc++){
      size_t cbase = base + (size_t)(c0 + cc) * 4096;
      #pragma unroll
      for(int u = 0; u < 2; u++){
        int e = u * 256 + t;
        int x = e >> 3, yh = e & 7;
        size_t src = cbase + (size_t)((x >> 3) * 512 + (x & 7) * 8 + yh * 64);
        int dst = yh * 8;
        *(f16x8*)(&Ah[cc][x][dst]) = *(const f16x8*)(Qh + src);
        *(f16x8*)(&Al[cc][x][dst]) = *(const f16x8*)(Ql + src);
        *(f16x8*)(&Bh[cc][x][dst]) = *(const f16x8*)(Kh + src);
        *(f16x8*)(&Bl[cc][x][dst]) = *(const f16x8*)(Kl + src);
      }
    }
    __syncthreads();
    #pragma unroll
    for(int cc = 0; cc < 2; cc++){
      #pragma unroll
      for(int kc = 0; kc < 2; kc++){
        f16x8 ah[2], alo[2], bh[2], blo[2];
        #pragma unroll
        for(int mi = 0; mi < 2; mi++){
          ah[mi]  = *(const f16x8*)(&Ah[cc][wm + mi * 16 + lr][kc * 32 + lg * 8]);
          alo[mi] = *(const f16x8*)(&Al[cc][wm + mi * 16 + lr][kc * 32 + lg * 8]);
        }
        #pragma unroll
        for(int ni = 0; ni < 2; ni++){
          bh[ni]  = *(const f16x8*)(&Bh[cc][wn + ni * 16 + lr][kc * 32 + lg * 8]);
          blo[ni] = *(const f16x8*)(&Bl[cc][wn + ni * 16 + lr][kc * 32 + lg * 8]);
        }
        #pragma unroll
        for(int mi = 0; mi < 2; mi++){
          #pragma unroll
          for(int ni = 0; ni < 2; ni++){
            f32x4 a = acc[mi][ni];
            a = mfma16(ah[mi],  bh[ni],  a);
            a = mfma16(ah[mi],  blo[ni], a);
            a = mfma16(alo[mi], bh[ni],  a);
            acc[mi][ni] = a;
          }
        }
      }
    }
  }
  float* outp = pa1p + ((size_t)bh * 8 + slice) * 4096;
  #pragma unroll
  for(int mi = 0; mi < 2; mi++){
    #pragma unroll
    for(int ni = 0; ni < 2; ni++){
      #pragma unroll
      for(int j = 0; j < 4; j++){
        int x = wm + mi * 16 + lg * 4 + j;
        int z = wn + ni * 16 + lr;
        outp[x * 64 + z] = acc[mi][ni][j];
      }
    }
  }
}

// ============ 6b. reduce partials + argmax (first max, np semantics) ============
__global__ __launch_bounds__(64) void k_pa1r(
    const float* __restrict__ pa1p, int* __restrict__ idx)
{
  const int bh = blockIdx.x;
  const int x = threadIdx.x;
  const float* p = pa1p + (size_t)bh * 8 * 4096 + x * 64;
  float best = -1e30f; int bi = 0;
  for(int z = 0; z < 64; z += 4){
    float4 v = *(const float4*)(p + z);
    #pragma unroll
    for(int sl = 1; sl < 8; sl++){
      float4 w = *(const float4*)(p + sl * 4096 + z);
      v.x += w.x; v.y += w.y; v.z += w.z; v.w += w.w;
    }
    if(v.x > best){ best = v.x; bi = z; }
    if(v.y > best){ best = v.y; bi = z + 1; }
    if(v.z > best){ best = v.z; bi = z + 2; }
    if(v.w > best){ best = v.w; bi = z + 3; }
  }
  idx[bh * 64 + x] = bi;
}

// ============ 7. PA intra-block attention (hi-only operands, XCD-swizzled grid) ============
__global__ __launch_bounds__(256) void k_pa2(
    const f16* __restrict__ Qh, const f16* __restrict__ Kh,
    const f16* __restrict__ V2, const int* __restrict__ idx, f16* __restrict__ Out)
{
  // swizzle: all 64 x-blocks of one bh land on one XCD (hw%8 assumed = XCD)
  const int hw = blockIdx.x;
  const int bh = (hw & 7) * 4 + ((hw >> 3) >> 6);
  const int x  = (hw >> 3) & 63;
  const size_t base = (size_t)bh * 64 * 4096;
  f16* Ob = Out + base;
  __shared__ float ql[64][65];
  __shared__ float kl[64][65];  // later reused as output staging [c][y]
  __shared__ f16 vl[64][72];
  __shared__ f16 pl[64][72];
  const int t = threadIdx.x;
  const int xk = idx[bh * 64 + x];
  const int xb = (x >> 3) * 512 + (x & 7) * 8;
  const int kb = (xk >> 3) * 512 + (xk & 7) * 8;
  {
    const int c = t >> 2, q4 = t & 3;
    #pragma unroll
    for(int u = 0; u < 2; u++){
      int yh = q4 * 2 + u;
      size_t offq = base + (size_t)c * 4096 + xb + yh * 64;
      size_t offk = base + (size_t)c * 4096 + kb + yh * 64;
      f16x8 qh8 = *(const f16x8*)(Qh + offq);
      f16x8 kh8 = *(const f16x8*)(Kh + offk);
      f16x8 vh8 = *(const f16x8*)(V2 + offk);
      #pragma unroll
      for(int j = 0; j < 8; j++){
        ql[c][yh * 8 + j] = (float)qh8[j];
        kl[c][yh * 8 + j] = (float)kh8[j];
      }
      *(f16x8*)(&vl[c][yh * 8]) = vh8;
    }
  }
  __syncthreads();
  const int y = t >> 2, zp = t & 3;
  float l[16];
  #pragma unroll
  for(int i = 0; i < 16; i++) l[i] = 0.f;
  for(int c = 0; c < 64; c++){
    float qv = ql[c][y];
    #pragma unroll
    for(int i = 0; i < 16; i++) l[i] += qv * kl[c][zp * 16 + i];
  }
  float m = l[0];
  #pragma unroll
  for(int i = 1; i < 16; i++) m = fmaxf(m, l[i]);
  m = fmaxf(m, __shfl_xor(m, 1)); m = fmaxf(m, __shfl_xor(m, 2));
  float sum = 0.f;
  #pragma unroll
  for(int i = 0; i < 16; i++){ l[i] = expf(l[i] - m); sum += l[i]; }
  sum += __shfl_xor(sum, 1); sum += __shfl_xor(sum, 2);
  float inv = 1.f / sum;
  #pragma unroll
  for(int i = 0; i < 16; i++) pl[y][zp * 16 + i] = (f16)(l[i] * inv);
  __syncthreads();  // all kl reads (logits) done; pl visible
  const int y2 = t >> 2, cp = t & 3;
  float ov[16];
  #pragma unroll
  for(int j = 0; j < 16; j++) ov[j] = 0.f;
  for(int z = 0; z < 64; z++){
    float pz = (float)pl[y2][z];
    #pragma unroll
    for(int j = 0; j < 16; j++) ov[j] += pz * (float)vl[cp * 16 + j][z];
  }
  #pragma unroll
  for(int j = 0; j < 16; j++) kl[cp * 16 + j][y2] = ov[j];
  __syncthreads();
  {
    const int c = t >> 2, yp = t & 3;
    #pragma unroll
    for(int u = 0; u < 2; u++){
      int yh = yp * 2 + u;
      f16x8 w;
      #pragma unroll
      for(int j = 0; j < 8; j++) w[j] = (f16)kl[c][yh * 8 + j];
      *(f16x8*)(Ob + (size_t)c * 4096 + xb + yh * 64) = w;
    }
  }
}

// ============ 8. Fused output: f1*DA + f2*PA + biases + content -> f32 ============
__global__ __launch_bounds__(256) void k_final(
    const f16* __restrict__ X1, const float* __restrict__ W1, const float* __restrict__ B1,
    const f16* __restrict__ X2, const float* __restrict__ W2, const float* __restrict__ B2,
    const float* __restrict__ content, float* __restrict__ out)
{
  const int b = blockIdx.z;
  const int o0 = blockIdx.y * 128;
  const int s0 = blockIdx.x * 128;
  __shared__ f16 As[128 * LSTR];
  __shared__ f16 Bs[128 * LSTR];
  const int t = threadIdx.x;
  const int lane = t & 63, wid = t >> 6;
  const int wm = (wid >> 1) * 64, wn = (wid & 1) * 64;
  const int lr = lane & 15, lg = lane >> 4;
  f32x4 acc[4][4] = {};
  for(int pass = 0; pass < 2; pass++){
    const f16* Xb = (pass ? X2 : X1) + (size_t)b * 512 * 4096;
    const float* Wp = pass ? W2 : W1;
    for(int kk = 0; kk < 512; kk += 32){
      __syncthreads();
      #pragma unroll
      for(int rep = 0; rep < 4; rep++){
        int q = t + 256 * rep;
        int row = q >> 3, c4 = q & 7;
        float4 w4 = *(const float4*)(Wp + (size_t)(o0 + row) * 512 + kk + c4 * 4);
        f16* dst = As + row * LSTR + c4 * 4;
        dst[0] = (f16)w4.x; dst[1] = (f16)w4.y; dst[2] = (f16)w4.z; dst[3] = (f16)w4.w;
      }
      #pragma unroll
      for(int rep = 0; rep < 2; rep++){
        int q = t + 256 * rep;
        int kr = q >> 4, s8 = q & 15;
        f16x8 v = *(const f16x8*)(Xb + (size_t)(kk + kr) * 4096 + s0 + s8 * 8);
        #pragma unroll
        for(int j = 0; j < 8; j++){
          int jj = (j + s8) & 7;
          Bs[(s8 * 8 + jj) * LSTR + kr] = v[jj];
        }
      }
      __syncthreads();
      f16x8 av[4], bv[4];
      #pragma unroll
      for(int mi = 0; mi < 4; mi++)
        av[mi] = *(const f16x8*)(As + (wm + mi * 16 + lr) * LSTR + lg * 8);
      #pragma unroll
      for(int ni = 0; ni < 4; ni++)
        bv[ni] = *(const f16x8*)(Bs + (wn + ni * 16 + lr) * LSTR + lg * 8);
      #pragma unroll
      for(int mi = 0; mi < 4; mi++){
        #pragma unroll
        for(int ni = 0; ni < 4; ni++)
          acc[mi][ni] = mfma16(av[mi], bv[ni], acc[mi][ni]);
      }
    }
  }
  #pragma unroll
  for(int mi = 0; mi < 4; mi++){
    #pragma unroll
    for(int ni = 0; ni < 4; ni++){
      #pragma unroll
      for(int j = 0; j < 4; j++){
        int o = o0 + wm + mi * 16 + lg * 4 + j;
        int s = s0 + wn + ni * 16 + lr;
        size_t gi = ((size_t)b * 512 + o) * 4096 + s;
        out[gi] = acc[mi][ni][j] + B1[o] + B2[o] + content[gi];
      }
    }
  }
}

extern "C" void kernel_launch(void* const* d_in, const int* in_sizes, int n_in,
                              void* d_out, int out_size, void* d_ws, size_t ws_size,
                              hipStream_t stream) {
  (void)in_sizes; (void)n_in; (void)out_size; (void)ws_size;
  const float* content = (const float*)d_in[0];
  const float* style   = (const float*)d_in[1];
  const float* q_w  = (const float*)d_in[2];  const float* q_b  = (const float*)d_in[3];
  const float* k_w  = (const float*)d_in[4];  const float* k_b  = (const float*)d_in[5];
  const float* v_w  = (const float*)d_in[6];  const float* v_b  = (const float*)d_in[7];
  const float* q2_w = (const float*)d_in[8];  const float* q2_b = (const float*)d_in[9];
  const float* k2_w = (const float*)d_in[10]; const float* k2_b = (const float*)d_in[11];
  const float* v2_w = (const float*)d_in[12]; const float* v2_b = (const float*)d_in[13];
  const float* f1_w = (const float*)d_in[14]; const float* f1_b = (const float*)d_in[15];
  const float* f2_w = (const float*)d_in[16]; const float* f2_b = (const float*)d_in[17];
  const float* sim_alpha = (const float*)d_in[18];
  const float* sim_beta  = (const float*)d_in[19];

  char* ws = (char*)d_ws;
  f16*   q2h  = (f16*)(ws + 0);                // 16,777,216 B
  f16*   q2l  = (f16*)(ws + 16777216);         // 16,777,216 B
  f16*   k2h  = (f16*)(ws + 33554432);         // 16,777,216 B
  f16*   k2l  = (f16*)(ws + 50331648);         // 16,777,216 B
  f16*   qbuf = (f16*)(ws + 67108864);         // 16,777,216 B
  f16*   kbuf = (f16*)(ws + 83886080);         // 16,777,216 B
  f16*   vbuf = (f16*)(ws + 100663296);        // 16,777,216 B
  f16*   dabuf= (f16*)(ws + 117440512);        // 16,777,216 B
  f16*   v2buf= (f16*)(ws + 67108864);         // reuses qbuf slot (after da2)
  f16*   pabuf= (f16*)(ws + 83886080);         // reuses kbuf slot (after da1)
  float* pa1p = (float*)(ws + 100663296);      // reuses vbuf slot (after da1), 4 MB
  float* stats= (float*)(ws + 134217728);      // 32,768 B
  float* kagg = (float*)(ws + 134250496);      // 524,288 B
  float* vagg = (float*)(ws + 134774784);      // 524,288 B
  int*   idxb = (int*)(ws + 135299072);        // 8,192 B

  dim3 gconv(32, 4, 4);

  k_mvn_stats<<<4096, 256, 0, stream>>>(content, style, stats);

  // precision-critical path (feeds argmax): fp16-split, hi/lo f16 outputs
  k_conv_hp<<<gconv, 256, 0, stream>>>(content, q2_w, q2_b, stats, 0,    q2h, q2l);
  k_conv_hp<<<gconv, 256, 0, stream>>>(style,   k2_w, k2_b, stats, 4096, k2h, k2l);

  // softmax-tolerant paths: plain fp16
  k_conv_h<<<gconv, 256, 0, stream>>>(content, q_w, q_b, stats, 0,    qbuf);
  k_conv_h<<<gconv, 256, 0, stream>>>(style,   k_w, k_b, stats, 4096, kbuf);
  k_conv_h<<<gconv, 256, 0, stream>>>(style,   v_w, v_b, stats, -1,   vbuf);

  k_da1<<<2048, 256, 0, stream>>>(kbuf, vbuf, sim_alpha, sim_beta, kagg, vagg);
  k_da2<<<512, 256, 0, stream>>>(qbuf, kagg, vagg, dabuf);

  k_conv_h<<<gconv, 256, 0, stream>>>(style, v2_w, v2_b, stats, -1, v2buf); // after da2 (reuses q slot)

  k_pa1<<<256, 256, 0, stream>>>(q2h, q2l, k2h, k2l, pa1p);   // after da1 (pa1p reuses v slot)
  k_pa1r<<<32, 64, 0, stream>>>(pa1p, idxb);
  k_pa2<<<2048, 256, 0, stream>>>(q2h, k2h, v2buf, idxb, pabuf);

  k_final<<<gconv, 256, 0, stream>>>(dabuf, f1_w, f1_b, pabuf, f2_w, f2_b,
                                     content, (float*)d_out);
}

// Round 4
// 546.719 us; speedup vs baseline: 1.3576x; 1.1815x over previous
//
#include <hip/hip_runtime.h>

typedef unsigned short u16;
typedef unsigned int   u32;
typedef _Float16       f16;

typedef f16   f16x8 __attribute__((ext_vector_type(8)));
typedef float f32x4 __attribute__((ext_vector_type(4)));

#define LSTR 40  // LDS row stride (elements) for 128x32 conv tiles; 40*2B=80B keeps 16B alignment

__device__ __forceinline__ f32x4 mfma16(f16x8 a, f16x8 b, f32x4 c){
  return __builtin_amdgcn_mfma_f32_16x16x32_f16(a, b, c, 0, 0, 0);
}

// ============ 1. per-(b,c) spatial mean / rstd for content & style ============
__global__ __launch_bounds__(256) void k_mvn_stats(
    const float* __restrict__ content, const float* __restrict__ style,
    float* __restrict__ stats)
{
  const int src = blockIdx.x >> 11;     // 0=content, 1=style
  const int row = blockIdx.x & 2047;    // b*512 + c
  const float* xp = (src ? style : content) + (size_t)row * 4096;
  const int t = threadIdx.x;
  double s = 0.0, ss = 0.0;
  for(int i = t * 4; i < 4096; i += 1024){
    float4 v = *(const float4*)(xp + i);
    s  += (double)v.x + (double)v.y + (double)v.z + (double)v.w;
    ss += (double)v.x * v.x + (double)v.y * v.y + (double)v.z * v.z + (double)v.w * v.w;
  }
  #pragma unroll
  for(int off = 32; off > 0; off >>= 1){
    s  += __shfl_xor(s, off);
    ss += __shfl_xor(ss, off);
  }
  __shared__ double sh[8];
  const int wid = t >> 6;
  if((t & 63) == 0){ sh[wid] = s; sh[4 + wid] = ss; }
  __syncthreads();
  if(t == 0){
    double S  = sh[0] + sh[1] + sh[2] + sh[3];
    double SS = sh[4] + sh[5] + sh[6] + sh[7];
    float mean = (float)(S * (1.0 / 4096.0));
    float var  = (float)((SS - S * S * (1.0 / 4096.0)) * (1.0 / 4095.0)); // ddof=1
    stats[src * 4096 + row] = mean;
    stats[src * 4096 + 2048 + row] = rsqrtf(var + 1e-5f);
  }
}

// ============ 2. conv1x1 GEMM, fp16 MFMA single-pass, fp16 output ============
__global__ __launch_bounds__(256) void k_conv_h(
    const float* __restrict__ X, const float* __restrict__ Wm,
    const float* __restrict__ bias, const float* __restrict__ stats,
    int norm_off, f16* __restrict__ Out)
{
  const int b = blockIdx.z;
  const int o0 = blockIdx.y * 128;
  const int s0 = blockIdx.x * 128;
  const float* Xb = X + (size_t)b * 512 * 4096;
  f16* Ob = Out + (size_t)b * 512 * 4096;
  __shared__ f16 As[128 * LSTR];
  __shared__ f16 Bs[128 * LSTR];
  const int t = threadIdx.x;
  const int lane = t & 63, wid = t >> 6;
  const int wm = (wid >> 1) * 64, wn = (wid & 1) * 64;
  const int lr = lane & 15, lg = lane >> 4;
  f32x4 acc[4][4] = {};
  for(int kk = 0; kk < 512; kk += 32){
    __syncthreads();
    #pragma unroll
    for(int rep = 0; rep < 4; rep++){
      int q = t + 256 * rep;
      int row = q >> 3, c4 = q & 7;
      float4 w4 = *(const float4*)(Wm + (size_t)(o0 + row) * 512 + kk + c4 * 4);
      f16* dst = As + row * LSTR + c4 * 4;
      dst[0] = (f16)w4.x; dst[1] = (f16)w4.y; dst[2] = (f16)w4.z; dst[3] = (f16)w4.w;
    }
    #pragma unroll
    for(int rep = 0; rep < 4; rep++){
      int q = t + 256 * rep;
      int kr = q >> 5, s4 = q & 31;
      int c = kk + kr;
      float4 x4 = *(const float4*)(Xb + (size_t)c * 4096 + s0 + s4 * 4);
      if(norm_off >= 0){
        float mean = stats[norm_off + b * 512 + c];
        float rstd = stats[norm_off + 2048 + b * 512 + c];
        x4.x = (x4.x - mean) * rstd; x4.y = (x4.y - mean) * rstd;
        x4.z = (x4.z - mean) * rstd; x4.w = (x4.w - mean) * rstd;
      }
      float xv[4] = {x4.x, x4.y, x4.z, x4.w};
      #pragma unroll
      for(int j = 0; j < 4; j++){
        int jj = (j + s4) & 3;
        Bs[(s4 * 4 + jj) * LSTR + kr] = (f16)xv[jj];
      }
    }
    __syncthreads();
    f16x8 av[4], bv[4];
    #pragma unroll
    for(int mi = 0; mi < 4; mi++)
      av[mi] = *(const f16x8*)(As + (wm + mi * 16 + lr) * LSTR + lg * 8);
    #pragma unroll
    for(int ni = 0; ni < 4; ni++)
      bv[ni] = *(const f16x8*)(Bs + (wn + ni * 16 + lr) * LSTR + lg * 8);
    #pragma unroll
    for(int mi = 0; mi < 4; mi++){
      #pragma unroll
      for(int ni = 0; ni < 4; ni++)
        acc[mi][ni] = mfma16(av[mi], bv[ni], acc[mi][ni]);
    }
  }
  #pragma unroll
  for(int mi = 0; mi < 4; mi++){
    #pragma unroll
    for(int ni = 0; ni < 4; ni++){
      #pragma unroll
      for(int j = 0; j < 4; j++){
        int o = o0 + wm + mi * 16 + lg * 4 + j;
        int s = s0 + wn + ni * 16 + lr;
        Ob[(size_t)o * 4096 + s] = (f16)(acc[mi][ni][j] + bias[o]);
      }
    }
  }
}

// ============ 3. conv1x1 GEMM, fp16-split (hi/lo) 3-pass MFMA, hi/lo f16 output ============
__global__ __launch_bounds__(256) void k_conv_hp(
    const float* __restrict__ X, const float* __restrict__ Wm,
    const float* __restrict__ bias, const float* __restrict__ stats,
    int norm_off, f16* __restrict__ Oh, f16* __restrict__ Ol)
{
  const int b = blockIdx.z;
  const int o0 = blockIdx.y * 128;
  const int s0 = blockIdx.x * 128;
  const float* Xb = X + (size_t)b * 512 * 4096;
  f16* Ohb = Oh + (size_t)b * 512 * 4096;
  f16* Olb = Ol + (size_t)b * 512 * 4096;
  __shared__ f16 Ah[128 * LSTR], Al[128 * LSTR], Bh[128 * LSTR], Bl[128 * LSTR];
  const int t = threadIdx.x;
  const int lane = t & 63, wid = t >> 6;
  const int wm = (wid >> 1) * 64, wn = (wid & 1) * 64;
  const int lr = lane & 15, lg = lane >> 4;
  f32x4 acc[4][4] = {};
  for(int kk = 0; kk < 512; kk += 32){
    __syncthreads();
    #pragma unroll
    for(int rep = 0; rep < 4; rep++){
      int q = t + 256 * rep;
      int row = q >> 3, c4 = q & 7;
      float4 w4 = *(const float4*)(Wm + (size_t)(o0 + row) * 512 + kk + c4 * 4);
      float wv[4] = {w4.x, w4.y, w4.z, w4.w};
      #pragma unroll
      for(int j = 0; j < 4; j++){
        f16 h = (f16)wv[j];
        f16 lo = (f16)(wv[j] - (float)h);
        Ah[row * LSTR + c4 * 4 + j] = h;
        Al[row * LSTR + c4 * 4 + j] = lo;
      }
    }
    #pragma unroll
    for(int rep = 0; rep < 4; rep++){
      int q = t + 256 * rep;
      int kr = q >> 5, s4 = q & 31;
      int c = kk + kr;
      float4 x4 = *(const float4*)(Xb + (size_t)c * 4096 + s0 + s4 * 4);
      if(norm_off >= 0){
        float mean = stats[norm_off + b * 512 + c];
        float rstd = stats[norm_off + 2048 + b * 512 + c];
        x4.x = (x4.x - mean) * rstd; x4.y = (x4.y - mean) * rstd;
        x4.z = (x4.z - mean) * rstd; x4.w = (x4.w - mean) * rstd;
      }
      float xv[4] = {x4.x, x4.y, x4.z, x4.w};
      #pragma unroll
      for(int j = 0; j < 4; j++){
        int jj = (j + s4) & 3;
        f16 h = (f16)xv[jj];
        f16 lo = (f16)(xv[jj] - (float)h);
        Bh[(s4 * 4 + jj) * LSTR + kr] = h;
        Bl[(s4 * 4 + jj) * LSTR + kr] = lo;
      }
    }
    __syncthreads();
    f16x8 ah[4], alo[4], bh[4], blo[4];
    #pragma unroll
    for(int mi = 0; mi < 4; mi++){
      ah[mi]  = *(const f16x8*)(Ah + (wm + mi * 16 + lr) * LSTR + lg * 8);
      alo[mi] = *(const f16x8*)(Al + (wm + mi * 16 + lr) * LSTR + lg * 8);
    }
    #pragma unroll
    for(int ni = 0; ni < 4; ni++){
      bh[ni]  = *(const f16x8*)(Bh + (wn + ni * 16 + lr) * LSTR + lg * 8);
      blo[ni] = *(const f16x8*)(Bl + (wn + ni * 16 + lr) * LSTR + lg * 8);
    }
    #pragma unroll
    for(int mi = 0; mi < 4; mi++){
      #pragma unroll
      for(int ni = 0; ni < 4; ni++){
        f32x4 a = acc[mi][ni];
        a = mfma16(ah[mi],  bh[ni],  a);
        a = mfma16(ah[mi],  blo[ni], a);
        a = mfma16(alo[mi], bh[ni],  a);
        acc[mi][ni] = a;
      }
    }
  }
  #pragma unroll
  for(int mi = 0; mi < 4; mi++){
    #pragma unroll
    for(int ni = 0; ni < 4; ni++){
      #pragma unroll
      for(int j = 0; j < 4; j++){
        int o = o0 + wm + mi * 16 + lg * 4 + j;
        int s = s0 + wn + ni * 16 + lr;
        float v = acc[mi][ni][j] + bias[o];
        f16 h = (f16)v;
        Ohb[(size_t)o * 4096 + s] = h;
        Olb[(size_t)o * 4096 + s] = (f16)(v - (float)h);
      }
    }
  }
}

// ============ 4. DA aggregation: k_c, sim=sigmoid(b+a*dis), k/v_agg ============
__global__ __launch_bounds__(256) void k_da1(
    const f16* __restrict__ K, const f16* __restrict__ V,
    const float* __restrict__ alpha_p, const float* __restrict__ beta_p,
    float* __restrict__ kagg, float* __restrict__ vagg)
{
  const int x = blockIdx.x & 63, bh = blockIdx.x >> 6;
  const f16* Kb = K + (size_t)bh * 64 * 4096;
  const f16* Vb = V + (size_t)bh * 64 * 4096;
  __shared__ float kl[64][65];
  __shared__ float vl[64][65];
  __shared__ float kc[64], vc[64], simv[64];
  const int t = threadIdx.x;
  const int c = t >> 2, yp = t & 3;
  const int xb = (x >> 3) * 512 + (x & 7) * 8;
  #pragma unroll
  for(int u = 0; u < 2; u++){
    int yh = yp * 2 + u;
    f16x8 k8 = *(const f16x8*)(Kb + (size_t)c * 4096 + xb + yh * 64);
    f16x8 v8 = *(const f16x8*)(Vb + (size_t)c * 4096 + xb + yh * 64);
    #pragma unroll
    for(int j = 0; j < 8; j++){
      kl[c][yh * 8 + j] = (float)k8[j];
      vl[c][yh * 8 + j] = (float)v8[j];
    }
  }
  __syncthreads();
  float sk = 0.f, sv = 0.f;
  for(int yy = yp * 16; yy < yp * 16 + 16; yy++){ sk += kl[c][yy]; sv += vl[c][yy]; }
  sk += __shfl_xor(sk, 1); sk += __shfl_xor(sk, 2);
  sv += __shfl_xor(sv, 1); sv += __shfl_xor(sv, 2);
  if(yp == 0){ kc[c] = sk * (1.f / 64.f); vc[c] = sv * (1.f / 64.f); }
  __syncthreads();
  const int y = t >> 2, cp = t & 3;
  float d = 0.f;
  for(int cc = cp * 16; cc < cp * 16 + 16; cc++) d += kc[cc] * kl[cc][y];
  d += __shfl_xor(d, 1); d += __shfl_xor(d, 2);
  if(cp == 0) simv[y] = 1.f / (1.f + expf(-(beta_p[0] + alpha_p[0] * d)));
  __syncthreads();
  float ak = 0.f, av = 0.f;
  for(int yy = yp * 16; yy < yp * 16 + 16; yy++){
    float sm = simv[yy];
    ak += sm * kl[c][yy]; av += sm * vl[c][yy];
  }
  ak += __shfl_xor(ak, 1); ak += __shfl_xor(ak, 2);
  av += __shfl_xor(av, 1); av += __shfl_xor(av, 2);
  if(yp == 0){
    size_t o = ((size_t)bh * 64 + x) * 64 + c;
    kagg[o] = (ak + kc[c]) * (1.f / 65.f);
    vagg[o] = (av + vc[c]) * (1.f / 65.f);
  }
}

// ============ 5. DA attention: per-query softmax over 64 aggregated keys ============
__global__ __launch_bounds__(256) void k_da2(
    const f16* __restrict__ Q, const float* __restrict__ kagg,
    const float* __restrict__ vagg, f16* __restrict__ Out)
{
  const int bh = blockIdx.x >> 4;
  const int s = ((blockIdx.x & 15) << 8) + threadIdx.x;
  const f16* Qb = Q + (size_t)bh * 64 * 4096;
  f16* Ob = Out + (size_t)bh * 64 * 4096;
  __shared__ float kz[4096];
  __shared__ float vz[4096];
  const int t = threadIdx.x;
  #pragma unroll
  for(int rep = 0; rep < 4; rep++){
    int o = (t + rep * 256) * 4;
    *(float4*)(kz + o) = *(const float4*)(kagg + (size_t)bh * 4096 + o);
    *(float4*)(vz + o) = *(const float4*)(vagg + (size_t)bh * 4096 + o);
  }
  __syncthreads();
  float lg[64];
  #pragma unroll
  for(int z = 0; z < 64; z++) lg[z] = 0.f;
  for(int c = 0; c < 64; c++){
    float qv = (float)Qb[(size_t)c * 4096 + s];
    #pragma unroll
    for(int z = 0; z < 64; z++) lg[z] += qv * kz[z * 64 + c];
  }
  float m = lg[0];
  #pragma unroll
  for(int z = 1; z < 64; z++) m = fmaxf(m, lg[z]);
  float sum = 0.f;
  #pragma unroll
  for(int z = 0; z < 64; z++){ lg[z] = expf(lg[z] - m); sum += lg[z]; }
  float inv = 1.f / sum;
  for(int c = 0; c < 64; c++){
    float a = 0.f;
    #pragma unroll
    for(int z = 0; z < 64; z++) a += lg[z] * vz[z * 64 + c];
    Ob[(size_t)c * 4096 + s] = (f16)(a * inv);
  }
}

// ============ 6. PA1 as split-K MFMA GEMM: PA1[x,z] = sum_{c,y} Q[c,x,y]K[c,z,y] ============
__global__ __launch_bounds__(256) void k_pa1(
    const f16* __restrict__ Qh, const f16* __restrict__ Ql,
    const f16* __restrict__ Kh, const f16* __restrict__ Kl,
    float* __restrict__ pa1p)
{
  const int slice = blockIdx.x & 7;
  const int bh = blockIdx.x >> 3;
  const size_t base = (size_t)bh * 64 * 4096;
  __shared__ f16 Ah[2][64][72], Al[2][64][72], Bh[2][64][72], Bl[2][64][72];
  const int t = threadIdx.x;
  const int lane = t & 63, wid = t >> 6;
  const int wm = (wid >> 1) * 32, wn = (wid & 1) * 32;
  const int lr = lane & 15, lg = lane >> 4;
  f32x4 acc[2][2] = {};
  for(int chunk = 0; chunk < 4; chunk++){
    const int c0 = slice * 8 + chunk * 2;
    __syncthreads();
    #pragma unroll
    for(int cc = 0; cc < 2; cc++){
      size_t cbase = base + (size_t)(c0 + cc) * 4096;
      #pragma unroll
      for(int u = 0; u < 2; u++){
        int e = u * 256 + t;
        int x = e >> 3, yh = e & 7;
        size_t src = cbase + (size_t)((x >> 3) * 512 + (x & 7) * 8 + yh * 64);
        int dst = yh * 8;
        *(f16x8*)(&Ah[cc][x][dst]) = *(const f16x8*)(Qh + src);
        *(f16x8*)(&Al[cc][x][dst]) = *(const f16x8*)(Ql + src);
        *(f16x8*)(&Bh[cc][x][dst]) = *(const f16x8*)(Kh + src);
        *(f16x8*)(&Bl[cc][x][dst]) = *(const f16x8*)(Kl + src);
      }
    }
    __syncthreads();
    #pragma unroll
    for(int cc = 0; cc < 2; cc++){
      #pragma unroll
      for(int kc = 0; kc < 2; kc++){
        f16x8 ah[2], alo[2], bh[2], blo[2];
        #pragma unroll
        for(int mi = 0; mi < 2; mi++){
          ah[mi]  = *(const f16x8*)(&Ah[cc][wm + mi * 16 + lr][kc * 32 + lg * 8]);
          alo[mi] = *(const f16x8*)(&Al[cc][wm + mi * 16 + lr][kc * 32 + lg * 8]);
        }
        #pragma unroll
        for(int ni = 0; ni < 2; ni++){
          bh[ni]  = *(const f16x8*)(&Bh[cc][wn + ni * 16 + lr][kc * 32 + lg * 8]);
          blo[ni] = *(const f16x8*)(&Bl[cc][wn + ni * 16 + lr][kc * 32 + lg * 8]);
        }
        #pragma unroll
        for(int mi = 0; mi < 2; mi++){
          #pragma unroll
          for(int ni = 0; ni < 2; ni++){
            f32x4 a = acc[mi][ni];
            a = mfma16(ah[mi],  bh[ni],  a);
            a = mfma16(ah[mi],  blo[ni], a);
            a = mfma16(alo[mi], bh[ni],  a);
            acc[mi][ni] = a;
          }
        }
      }
    }
  }
  float* outp = pa1p + ((size_t)bh * 8 + slice) * 4096;
  #pragma unroll
  for(int mi = 0; mi < 2; mi++){
    #pragma unroll
    for(int ni = 0; ni < 2; ni++){
      #pragma unroll
      for(int j = 0; j < 4; j++){
        int x = wm + mi * 16 + lg * 4 + j;
        int z = wn + ni * 16 + lr;
        outp[x * 64 + z] = acc[mi][ni][j];
      }
    }
  }
}

// ============ 6b. reduce partials + argmax (first max, np semantics) ============
__global__ __launch_bounds__(64) void k_pa1r(
    const float* __restrict__ pa1p, int* __restrict__ idx)
{
  const int bh = blockIdx.x;
  const int x = threadIdx.x;
  const float* p = pa1p + (size_t)bh * 8 * 4096 + x * 64;
  float best = -1e30f; int bi = 0;
  for(int z = 0; z < 64; z += 4){
    float4 v = *(const float4*)(p + z);
    #pragma unroll
    for(int sl = 1; sl < 8; sl++){
      float4 w = *(const float4*)(p + sl * 4096 + z);
      v.x += w.x; v.y += w.y; v.z += w.z; v.w += w.w;
    }
    if(v.x > best){ best = v.x; bi = z; }
    if(v.y > best){ best = v.y; bi = z + 1; }
    if(v.z > best){ best = v.z; bi = z + 2; }
    if(v.w > best){ best = v.w; bi = z + 3; }
  }
  idx[bh * 64 + x] = bi;
}

// ============ 7. PA intra-block attention: 3-phase MFMA (logits / softmax / PV) ============
__global__ __launch_bounds__(256) void k_pa2(
    const f16* __restrict__ Qh, const f16* __restrict__ Kh,
    const f16* __restrict__ V2, const int* __restrict__ idx, f16* __restrict__ Out)
{
  // XCD swizzle: all 64 x-blocks of one bh land on one XCD (hw%8 assumed = XCD)
  const int hw = blockIdx.x;
  const int bh = (hw & 7) * 4 + ((hw >> 3) >> 6);
  const int x  = (hw >> 3) & 63;
  const size_t base = (size_t)bh * 64 * 4096;
  f16* Ob = Out + base;

  // Qt/Kt (f16 transposed, XOR-swizzled) overlaid later by Lf (f32 logits) then Os (f32 out)
  __shared__ __align__(16) char Ubuf[18432];
  __shared__ f16 Vn[64][72];   // V[c][z], natural layout
  __shared__ f16 Ps[64][72];   // P[y][z]
  f16   (*Qt)[72] = (f16(*)[72])Ubuf;            // Qt[y][swz(c)]
  f16   (*Kt)[72] = (f16(*)[72])(Ubuf + 9216);   // Kt[z][swz(c)]
  float (*Lf)[66] = (float(*)[66])Ubuf;          // logits [y][z]
  float (*Os)[67] = (float(*)[67])Ubuf;          // out staging [c][y]

  const int t = threadIdx.x;
  const int lane = t & 63, wid = t >> 6;
  const int wm = (wid >> 1) * 32, wn = (wid & 1) * 32;
  const int lr = lane & 15, lg = lane >> 4;

  const int xk = idx[bh * 64 + x];
  const int xb = (x >> 3) * 512 + (x & 7) * 8;
  const int kb = (xk >> 3) * 512 + (xk & 7) * 8;

  // ---- stage: Q,K transposed+swizzled; V natural ----
  {
    const int c = t >> 2, q4 = t & 3;
    #pragma unroll
    for(int u = 0; u < 2; u++){
      int yh = q4 * 2 + u;
      f16x8 q8 = *(const f16x8*)(Qh + base + (size_t)c * 4096 + xb + yh * 64);
      f16x8 k8 = *(const f16x8*)(Kh + base + (size_t)c * 4096 + kb + yh * 64);
      f16x8 v8 = *(const f16x8*)(V2 + base + (size_t)c * 4096 + kb + yh * 64);
      int col = ((((c >> 3) ^ yh) & 7) << 3) + (c & 7);  // conflict-free scatter
      #pragma unroll
      for(int j = 0; j < 8; j++){
        Qt[yh * 8 + j][col] = q8[j];
        Kt[yh * 8 + j][col] = k8[j];
      }
      *(f16x8*)(&Vn[c][yh * 8]) = v8;
    }
  }
  __syncthreads();

  // ---- phase 1: L[y][z] = sum_c Q[y][c] K[z][c] ----
  f32x4 acc[2][2] = {};
  #pragma unroll
  for(int kc = 0; kc < 2; kc++){
    f16x8 af[2], bf[2];
    #pragma unroll
    for(int mi = 0; mi < 2; mi++){
      int row = wm + mi * 16 + lr;
      af[mi] = *(const f16x8*)(&Qt[row][((((kc * 4 + lg) ^ (row >> 3)) & 7) << 3)]);
    }
    #pragma unroll
    for(int ni = 0; ni < 2; ni++){
      int row = wn + ni * 16 + lr;
      bf[ni] = *(const f16x8*)(&Kt[row][((((kc * 4 + lg) ^ (row >> 3)) & 7) << 3)]);
    }
    #pragma unroll
    for(int mi = 0; mi < 2; mi++){
      #pragma unroll
      for(int ni = 0; ni < 2; ni++)
        acc[mi][ni] = mfma16(af[mi], bf[ni], acc[mi][ni]);
    }
  }
  __syncthreads();  // all Qt/Kt reads done before Lf overlay write
  #pragma unroll
  for(int mi = 0; mi < 2; mi++){
    #pragma unroll
    for(int ni = 0; ni < 2; ni++){
      #pragma unroll
      for(int j = 0; j < 4; j++)
        Lf[wm + mi * 16 + lg * 4 + j][wn + ni * 16 + lr] = acc[mi][ni][j];
    }
  }
  __syncthreads();

  // ---- phase 2: row softmax (4 threads per row, 16 z each) ----
  {
    const int y = t >> 2, zp = t & 3;
    float l[16];
    #pragma unroll
    for(int i = 0; i < 16; i++) l[i] = Lf[y][zp * 16 + i];
    float m = l[0];
    #pragma unroll
    for(int i = 1; i < 16; i++) m = fmaxf(m, l[i]);
    m = fmaxf(m, __shfl_xor(m, 1)); m = fmaxf(m, __shfl_xor(m, 2));
    float sum = 0.f;
    #pragma unroll
    for(int i = 0; i < 16; i++){ l[i] = expf(l[i] - m); sum += l[i]; }
    sum += __shfl_xor(sum, 1); sum += __shfl_xor(sum, 2);
    float inv = 1.f / sum;
    f16x8 p0, p1;
    #pragma unroll
    for(int i = 0; i < 8; i++){ p0[i] = (f16)(l[i] * inv); p1[i] = (f16)(l[8 + i] * inv); }
    *(f16x8*)(&Ps[y][zp * 16]) = p0;
    *(f16x8*)(&Ps[y][zp * 16 + 8]) = p1;
  }
  __syncthreads();  // Ps visible; Lf reads done -> Os overlay safe

  // ---- phase 3: D[y][c] = sum_z P[y][z] V[c][z] ----
  f32x4 acc2[2][2] = {};
  #pragma unroll
  for(int kc = 0; kc < 2; kc++){
    f16x8 af[2], bf[2];
    #pragma unroll
    for(int mi = 0; mi < 2; mi++)
      af[mi] = *(const f16x8*)(&Ps[wm + mi * 16 + lr][kc * 32 + lg * 8]);
    #pragma unroll
    for(int ni = 0; ni < 2; ni++)
      bf[ni] = *(const f16x8*)(&Vn[wn + ni * 16 + lr][kc * 32 + lg * 8]);
    #pragma unroll
    for(int mi = 0; mi < 2; mi++){
      #pragma unroll
      for(int ni = 0; ni < 2; ni++)
        acc2[mi][ni] = mfma16(af[mi], bf[ni], acc2[mi][ni]);
    }
  }
  #pragma unroll
  for(int mi = 0; mi < 2; mi++){
    #pragma unroll
    for(int ni = 0; ni < 2; ni++){
      #pragma unroll
      for(int j = 0; j < 4; j++)
        Os[wn + ni * 16 + lr][wm + mi * 16 + lg * 4 + j] = acc2[mi][ni][j];
    }
  }
  __syncthreads();

  // ---- output: coalesced f16x8 stores ----
  {
    const int c = t >> 2, yp = t & 3;
    #pragma unroll
    for(int u = 0; u < 2; u++){
      int yh = yp * 2 + u;
      f16x8 w;
      #pragma unroll
      for(int j = 0; j < 8; j++) w[j] = (f16)Os[c][yh * 8 + j];
      *(f16x8*)(Ob + (size_t)c * 4096 + xb + yh * 64) = w;
    }
  }
}

// ============ 8. Fused output: f1*DA + f2*PA + biases + content -> f32 ============
__global__ __launch_bounds__(256) void k_final(
    const f16* __restrict__ X1, const float* __restrict__ W1, const float* __restrict__ B1,
    const f16* __restrict__ X2, const float* __restrict__ W2, const float* __restrict__ B2,
    const float* __restrict__ content, float* __restrict__ out)
{
  const int b = blockIdx.z;
  const int o0 = blockIdx.y * 128;
  const int s0 = blockIdx.x * 128;
  __shared__ f16 As[128 * LSTR];
  __shared__ f16 Bs[128 * LSTR];
  const int t = threadIdx.x;
  const int lane = t & 63, wid = t >> 6;
  const int wm = (wid >> 1) * 64, wn = (wid & 1) * 64;
  const int lr = lane & 15, lg = lane >> 4;
  f32x4 acc[4][4] = {};
  for(int pass = 0; pass < 2; pass++){
    const f16* Xb = (pass ? X2 : X1) + (size_t)b * 512 * 4096;
    const float* Wp = pass ? W2 : W1;
    for(int kk = 0; kk < 512; kk += 32){
      __syncthreads();
      #pragma unroll
      for(int rep = 0; rep < 4; rep++){
        int q = t + 256 * rep;
        int row = q >> 3, c4 = q & 7;
        float4 w4 = *(const float4*)(Wp + (size_t)(o0 + row) * 512 + kk + c4 * 4);
        f16* dst = As + row * LSTR + c4 * 4;
        dst[0] = (f16)w4.x; dst[1] = (f16)w4.y; dst[2] = (f16)w4.z; dst[3] = (f16)w4.w;
      }
      #pragma unroll
      for(int rep = 0; rep < 2; rep++){
        int q = t + 256 * rep;
        int kr = q >> 4, s8 = q & 15;
        f16x8 v = *(const f16x8*)(Xb + (size_t)(kk + kr) * 4096 + s0 + s8 * 8);
        #pragma unroll
        for(int j = 0; j < 8; j++){
          int jj = (j + s8) & 7;
          Bs[(s8 * 8 + jj) * LSTR + kr] = v[jj];
        }
      }
      __syncthreads();
      f16x8 av[4], bv[4];
      #pragma unroll
      for(int mi = 0; mi < 4; mi++)
        av[mi] = *(const f16x8*)(As + (wm + mi * 16 + lr) * LSTR + lg * 8);
      #pragma unroll
      for(int ni = 0; ni < 4; ni++)
        bv[ni] = *(const f16x8*)(Bs + (wn + ni * 16 + lr) * LSTR + lg * 8);
      #pragma unroll
      for(int mi = 0; mi < 4; mi++){
        #pragma unroll
        for(int ni = 0; ni < 4; ni++)
          acc[mi][ni] = mfma16(av[mi], bv[ni], acc[mi][ni]);
      }
    }
  }
  #pragma unroll
  for(int mi = 0; mi < 4; mi++){
    #pragma unroll
    for(int ni = 0; ni < 4; ni++){
      #pragma unroll
      for(int j = 0; j < 4; j++){
        int o = o0 + wm + mi * 16 + lg * 4 + j;
        int s = s0 + wn + ni * 16 + lr;
        size_t gi = ((size_t)b * 512 + o) * 4096 + s;
        out[gi] = acc[mi][ni][j] + B1[o] + B2[o] + content[gi];
      }
    }
  }
}

extern "C" void kernel_launch(void* const* d_in, const int* in_sizes, int n_in,
                              void* d_out, int out_size, void* d_ws, size_t ws_size,
                              hipStream_t stream) {
  (void)in_sizes; (void)n_in; (void)out_size; (void)ws_size;
  const float* content = (const float*)d_in[0];
  const float* style   = (const float*)d_in[1];
  const float* q_w  = (const float*)d_in[2];  const float* q_b  = (const float*)d_in[3];
  const float* k_w  = (const float*)d_in[4];  const float* k_b  = (const float*)d_in[5];
  const float* v_w  = (const float*)d_in[6];  const float* v_b  = (const float*)d_in[7];
  const float* q2_w = (const float*)d_in[8];  const float* q2_b = (const float*)d_in[9];
  const float* k2_w = (const float*)d_in[10]; const float* k2_b = (const float*)d_in[11];
  const float* v2_w = (const float*)d_in[12]; const float* v2_b = (const float*)d_in[13];
  const float* f1_w = (const float*)d_in[14]; const float* f1_b = (const float*)d_in[15];
  const float* f2_w = (const float*)d_in[16]; const float* f2_b = (const float*)d_in[17];
  const float* sim_alpha = (const float*)d_in[18];
  const float* sim_beta  = (const float*)d_in[19];

  char* ws = (char*)d_ws;
  f16*   q2h  = (f16*)(ws + 0);                // 16,777,216 B
  f16*   q2l  = (f16*)(ws + 16777216);         // 16,777,216 B
  f16*   k2h  = (f16*)(ws + 33554432);         // 16,777,216 B
  f16*   k2l  = (f16*)(ws + 50331648);         // 16,777,216 B
  f16*   qbuf = (f16*)(ws + 67108864);         // 16,777,216 B
  f16*   kbuf = (f16*)(ws + 83886080);         // 16,777,216 B
  f16*   vbuf = (f16*)(ws + 100663296);        // 16,777,216 B
  f16*   dabuf= (f16*)(ws + 117440512);        // 16,777,216 B
  f16*   v2buf= (f16*)(ws + 67108864);         // reuses qbuf slot (after da2)
  f16*   pabuf= (f16*)(ws + 83886080);         // reuses kbuf slot (after da1)
  float* pa1p = (float*)(ws + 100663296);      // reuses vbuf slot (after da1), 4 MB
  float* stats= (float*)(ws + 134217728);      // 32,768 B
  float* kagg = (float*)(ws + 134250496);      // 524,288 B
  float* vagg = (float*)(ws + 134774784);      // 524,288 B
  int*   idxb = (int*)(ws + 135299072);        // 8,192 B

  dim3 gconv(32, 4, 4);

  k_mvn_stats<<<4096, 256, 0, stream>>>(content, style, stats);

  // precision-critical path (feeds argmax): fp16-split, hi/lo f16 outputs
  k_conv_hp<<<gconv, 256, 0, stream>>>(content, q2_w, q2_b, stats, 0,    q2h, q2l);
  k_conv_hp<<<gconv, 256, 0, stream>>>(style,   k2_w, k2_b, stats, 4096, k2h, k2l);

  // softmax-tolerant paths: plain fp16
  k_conv_h<<<gconv, 256, 0, stream>>>(content, q_w, q_b, stats, 0,    qbuf);
  k_conv_h<<<gconv, 256, 0, stream>>>(style,   k_w, k_b, stats, 4096, kbuf);
  k_conv_h<<<gconv, 256, 0, stream>>>(style,   v_w, v_b, stats, -1,   vbuf);

  k_da1<<<2048, 256, 0, stream>>>(kbuf, vbuf, sim_alpha, sim_beta, kagg, vagg);
  k_da2<<<512, 256, 0, stream>>>(qbuf, kagg, vagg, dabuf);

  k_conv_h<<<gconv, 256, 0, stream>>>(style, v2_w, v2_b, stats, -1, v2buf); // after da2 (reuses q slot)

  k_pa1<<<256, 256, 0, stream>>>(q2h, q2l, k2h, k2l, pa1p);   // after da1 (pa1p reuses v slot)
  k_pa1r<<<32, 64, 0, stream>>>(pa1p, idxb);
  k_pa2<<<2048, 256, 0, stream>>>(q2h, k2h, v2buf, idxb, pabuf);

  k_final<<<gconv, 256, 0, stream>>>(dabuf, f1_w, f1_b, pabuf, f2_w, f2_b,
                                     content, (float*)d_out);
}

// Round 5
// 464.962 us; speedup vs baseline: 1.5964x; 1.1758x over previous
//
#include <hip/hip_runtime.h>

typedef unsigned short u16;
typedef unsigned int   u32;
typedef _Float16       f16;

typedef f16   f16x8 __attribute__((ext_vector_type(8)));
typedef f16   f16x4 __attribute__((ext_vector_type(4)));
typedef float f32x4 __attribute__((ext_vector_type(4)));

#define LSTR 40  // LDS row stride (elements) for 128x32 conv tiles; 40*2B=80B keeps 16B alignment

__device__ __forceinline__ f32x4 mfma16(f16x8 a, f16x8 b, f32x4 c){
  return __builtin_amdgcn_mfma_f32_16x16x32_f16(a, b, c, 0, 0, 0);
}

// ============ 1. per-(b,c) spatial mean / rstd for content & style ============
__global__ __launch_bounds__(256) void k_mvn_stats(
    const float* __restrict__ content, const float* __restrict__ style,
    float* __restrict__ stats)
{
  const int src = blockIdx.x >> 11;     // 0=content, 1=style
  const int row = blockIdx.x & 2047;    // b*512 + c
  const float* xp = (src ? style : content) + (size_t)row * 4096;
  const int t = threadIdx.x;
  double s = 0.0, ss = 0.0;
  for(int i = t * 4; i < 4096; i += 1024){
    float4 v = *(const float4*)(xp + i);
    s  += (double)v.x + (double)v.y + (double)v.z + (double)v.w;
    ss += (double)v.x * v.x + (double)v.y * v.y + (double)v.z * v.z + (double)v.w * v.w;
  }
  #pragma unroll
  for(int off = 32; off > 0; off >>= 1){
    s  += __shfl_xor(s, off);
    ss += __shfl_xor(ss, off);
  }
  __shared__ double sh[8];
  const int wid = t >> 6;
  if((t & 63) == 0){ sh[wid] = s; sh[4 + wid] = ss; }
  __syncthreads();
  if(t == 0){
    double S  = sh[0] + sh[1] + sh[2] + sh[3];
    double SS = sh[4] + sh[5] + sh[6] + sh[7];
    float mean = (float)(S * (1.0 / 4096.0));
    float var  = (float)((SS - S * S * (1.0 / 4096.0)) * (1.0 / 4095.0)); // ddof=1
    stats[src * 4096 + row] = mean;
    stats[src * 4096 + 2048 + row] = rsqrtf(var + 1e-5f);
  }
}

// ============ 2. conv1x1 GEMM, fp16 MFMA single-pass, fp16 output ============
__global__ __launch_bounds__(256) void k_conv_h(
    const float* __restrict__ X, const float* __restrict__ Wm,
    const float* __restrict__ bias, const float* __restrict__ stats,
    int norm_off, f16* __restrict__ Out)
{
  const int b = blockIdx.z;
  const int o0 = blockIdx.y * 128;
  const int s0 = blockIdx.x * 128;
  const float* Xb = X + (size_t)b * 512 * 4096;
  f16* Ob = Out + (size_t)b * 512 * 4096;
  __shared__ f16 As[128 * LSTR];
  __shared__ f16 Bs[128 * LSTR];
  const int t = threadIdx.x;
  const int lane = t & 63, wid = t >> 6;
  const int wm = (wid >> 1) * 64, wn = (wid & 1) * 64;
  const int lr = lane & 15, lg = lane >> 4;
  f32x4 acc[4][4] = {};
  for(int kk = 0; kk < 512; kk += 32){
    __syncthreads();
    #pragma unroll
    for(int rep = 0; rep < 4; rep++){
      int q = t + 256 * rep;
      int row = q >> 3, c4 = q & 7;
      float4 w4 = *(const float4*)(Wm + (size_t)(o0 + row) * 512 + kk + c4 * 4);
      f16* dst = As + row * LSTR + c4 * 4;
      dst[0] = (f16)w4.x; dst[1] = (f16)w4.y; dst[2] = (f16)w4.z; dst[3] = (f16)w4.w;
    }
    #pragma unroll
    for(int rep = 0; rep < 4; rep++){
      int q = t + 256 * rep;
      int kr = q >> 5, s4 = q & 31;
      int c = kk + kr;
      float4 x4 = *(const float4*)(Xb + (size_t)c * 4096 + s0 + s4 * 4);
      if(norm_off >= 0){
        float mean = stats[norm_off + b * 512 + c];
        float rstd = stats[norm_off + 2048 + b * 512 + c];
        x4.x = (x4.x - mean) * rstd; x4.y = (x4.y - mean) * rstd;
        x4.z = (x4.z - mean) * rstd; x4.w = (x4.w - mean) * rstd;
      }
      float xv[4] = {x4.x, x4.y, x4.z, x4.w};
      #pragma unroll
      for(int j = 0; j < 4; j++){
        int jj = (j + s4) & 3;
        Bs[(s4 * 4 + jj) * LSTR + kr] = (f16)xv[jj];
      }
    }
    __syncthreads();
    f16x8 av[4], bv[4];
    #pragma unroll
    for(int mi = 0; mi < 4; mi++)
      av[mi] = *(const f16x8*)(As + (wm + mi * 16 + lr) * LSTR + lg * 8);
    #pragma unroll
    for(int ni = 0; ni < 4; ni++)
      bv[ni] = *(const f16x8*)(Bs + (wn + ni * 16 + lr) * LSTR + lg * 8);
    #pragma unroll
    for(int mi = 0; mi < 4; mi++){
      #pragma unroll
      for(int ni = 0; ni < 4; ni++)
        acc[mi][ni] = mfma16(av[mi], bv[ni], acc[mi][ni]);
    }
  }
  #pragma unroll
  for(int mi = 0; mi < 4; mi++){
    #pragma unroll
    for(int ni = 0; ni < 4; ni++){
      #pragma unroll
      for(int j = 0; j < 4; j++){
        int o = o0 + wm + mi * 16 + lg * 4 + j;
        int s = s0 + wn + ni * 16 + lr;
        Ob[(size_t)o * 4096 + s] = (f16)(acc[mi][ni][j] + bias[o]);
      }
    }
  }
}

// ============ 3. conv1x1 GEMM, fp16-split (hi/lo) 3-pass MFMA, hi/lo f16 output ============
__global__ __launch_bounds__(256) void k_conv_hp(
    const float* __restrict__ X, const float* __restrict__ Wm,
    const float* __restrict__ bias, const float* __restrict__ stats,
    int norm_off, f16* __restrict__ Oh, f16* __restrict__ Ol)
{
  const int b = blockIdx.z;
  const int o0 = blockIdx.y * 128;
  const int s0 = blockIdx.x * 128;
  const float* Xb = X + (size_t)b * 512 * 4096;
  f16* Ohb = Oh + (size_t)b * 512 * 4096;
  f16* Olb = Ol + (size_t)b * 512 * 4096;
  __shared__ f16 Ah[128 * LSTR], Al[128 * LSTR], Bh[128 * LSTR], Bl[128 * LSTR];
  const int t = threadIdx.x;
  const int lane = t & 63, wid = t >> 6;
  const int wm = (wid >> 1) * 64, wn = (wid & 1) * 64;
  const int lr = lane & 15, lg = lane >> 4;
  f32x4 acc[4][4] = {};
  for(int kk = 0; kk < 512; kk += 32){
    __syncthreads();
    #pragma unroll
    for(int rep = 0; rep < 4; rep++){
      int q = t + 256 * rep;
      int row = q >> 3, c4 = q & 7;
      float4 w4 = *(const float4*)(Wm + (size_t)(o0 + row) * 512 + kk + c4 * 4);
      float wv[4] = {w4.x, w4.y, w4.z, w4.w};
      #pragma unroll
      for(int j = 0; j < 4; j++){
        f16 h = (f16)wv[j];
        f16 lo = (f16)(wv[j] - (float)h);
        Ah[row * LSTR + c4 * 4 + j] = h;
        Al[row * LSTR + c4 * 4 + j] = lo;
      }
    }
    #pragma unroll
    for(int rep = 0; rep < 4; rep++){
      int q = t + 256 * rep;
      int kr = q >> 5, s4 = q & 31;
      int c = kk + kr;
      float4 x4 = *(const float4*)(Xb + (size_t)c * 4096 + s0 + s4 * 4);
      if(norm_off >= 0){
        float mean = stats[norm_off + b * 512 + c];
        float rstd = stats[norm_off + 2048 + b * 512 + c];
        x4.x = (x4.x - mean) * rstd; x4.y = (x4.y - mean) * rstd;
        x4.z = (x4.z - mean) * rstd; x4.w = (x4.w - mean) * rstd;
      }
      float xv[4] = {x4.x, x4.y, x4.z, x4.w};
      #pragma unroll
      for(int j = 0; j < 4; j++){
        int jj = (j + s4) & 3;
        f16 h = (f16)xv[jj];
        f16 lo = (f16)(xv[jj] - (float)h);
        Bh[(s4 * 4 + jj) * LSTR + kr] = h;
        Bl[(s4 * 4 + jj) * LSTR + kr] = lo;
      }
    }
    __syncthreads();
    f16x8 ah[4], alo[4], bh[4], blo[4];
    #pragma unroll
    for(int mi = 0; mi < 4; mi++){
      ah[mi]  = *(const f16x8*)(Ah + (wm + mi * 16 + lr) * LSTR + lg * 8);
      alo[mi] = *(const f16x8*)(Al + (wm + mi * 16 + lr) * LSTR + lg * 8);
    }
    #pragma unroll
    for(int ni = 0; ni < 4; ni++){
      bh[ni]  = *(const f16x8*)(Bh + (wn + ni * 16 + lr) * LSTR + lg * 8);
      blo[ni] = *(const f16x8*)(Bl + (wn + ni * 16 + lr) * LSTR + lg * 8);
    }
    #pragma unroll
    for(int mi = 0; mi < 4; mi++){
      #pragma unroll
      for(int ni = 0; ni < 4; ni++){
        f32x4 a = acc[mi][ni];
        a = mfma16(ah[mi],  bh[ni],  a);
        a = mfma16(ah[mi],  blo[ni], a);
        a = mfma16(alo[mi], bh[ni],  a);
        acc[mi][ni] = a;
      }
    }
  }
  #pragma unroll
  for(int mi = 0; mi < 4; mi++){
    #pragma unroll
    for(int ni = 0; ni < 4; ni++){
      #pragma unroll
      for(int j = 0; j < 4; j++){
        int o = o0 + wm + mi * 16 + lg * 4 + j;
        int s = s0 + wn + ni * 16 + lr;
        float v = acc[mi][ni][j] + bias[o];
        f16 h = (f16)v;
        Ohb[(size_t)o * 4096 + s] = h;
        Olb[(size_t)o * 4096 + s] = (f16)(v - (float)h);
      }
    }
  }
}

// ============ 4. DA aggregation: k_c, sim=sigmoid(b+a*dis), k/v_agg ============
__global__ __launch_bounds__(256) void k_da1(
    const f16* __restrict__ K, const f16* __restrict__ V,
    const float* __restrict__ alpha_p, const float* __restrict__ beta_p,
    float* __restrict__ kagg, float* __restrict__ vagg)
{
  const int x = blockIdx.x & 63, bh = blockIdx.x >> 6;
  const f16* Kb = K + (size_t)bh * 64 * 4096;
  const f16* Vb = V + (size_t)bh * 64 * 4096;
  __shared__ float kl[64][65];
  __shared__ float vl[64][65];
  __shared__ float kc[64], vc[64], simv[64];
  const int t = threadIdx.x;
  const int c = t >> 2, yp = t & 3;
  const int xb = (x >> 3) * 512 + (x & 7) * 8;
  #pragma unroll
  for(int u = 0; u < 2; u++){
    int yh = yp * 2 + u;
    f16x8 k8 = *(const f16x8*)(Kb + (size_t)c * 4096 + xb + yh * 64);
    f16x8 v8 = *(const f16x8*)(Vb + (size_t)c * 4096 + xb + yh * 64);
    #pragma unroll
    for(int j = 0; j < 8; j++){
      kl[c][yh * 8 + j] = (float)k8[j];
      vl[c][yh * 8 + j] = (float)v8[j];
    }
  }
  __syncthreads();
  float sk = 0.f, sv = 0.f;
  for(int yy = yp * 16; yy < yp * 16 + 16; yy++){ sk += kl[c][yy]; sv += vl[c][yy]; }
  sk += __shfl_xor(sk, 1); sk += __shfl_xor(sk, 2);
  sv += __shfl_xor(sv, 1); sv += __shfl_xor(sv, 2);
  if(yp == 0){ kc[c] = sk * (1.f / 64.f); vc[c] = sv * (1.f / 64.f); }
  __syncthreads();
  const int y = t >> 2, cp = t & 3;
  float d = 0.f;
  for(int cc = cp * 16; cc < cp * 16 + 16; cc++) d += kc[cc] * kl[cc][y];
  d += __shfl_xor(d, 1); d += __shfl_xor(d, 2);
  if(cp == 0) simv[y] = 1.f / (1.f + expf(-(beta_p[0] + alpha_p[0] * d)));
  __syncthreads();
  float ak = 0.f, av = 0.f;
  for(int yy = yp * 16; yy < yp * 16 + 16; yy++){
    float sm = simv[yy];
    ak += sm * kl[c][yy]; av += sm * vl[c][yy];
  }
  ak += __shfl_xor(ak, 1); ak += __shfl_xor(ak, 2);
  av += __shfl_xor(av, 1); av += __shfl_xor(av, 2);
  if(yp == 0){
    size_t o = ((size_t)bh * 64 + x) * 64 + c;
    kagg[o] = (ak + kc[c]) * (1.f / 65.f);
    vagg[o] = (av + vc[c]) * (1.f / 65.f);
  }
}

// ============ 5. DA attention as MFMA: per block 256 queries x 64 keys, dim 64 ============
__global__ __launch_bounds__(256) void k_da2(
    const f16* __restrict__ Q, const float* __restrict__ kagg,
    const float* __restrict__ vagg, f16* __restrict__ Out)
{
  const int bh = blockIdx.x >> 4;
  const int s0 = (blockIdx.x & 15) << 8;
  const f16* Qb = Q + (size_t)bh * 64 * 4096;
  f16* Ob = Out + (size_t)bh * 64 * 4096;

  __shared__ __align__(16) f16 Qt[256][72];  // [s_local][swz c]; per-wave rows overlaid by P after logits
  __shared__ __align__(16) f16 Kt[64][72];   // [z][swz c]
  __shared__ __align__(16) f16 Vt[64][72];   // [c][swz z]
  const int t = threadIdx.x;
  const int lane = t & 63, w = t >> 6;
  const int lr = lane & 15, lg = lane >> 4;

  // ---- stage Q transposed (coalesced f16x8 along s, scatter to [s][swz c]) ----
  {
    const int so = t & 31;            // s-octet (32 per 256-query tile)
    #pragma unroll
    for(int pass = 0; pass < 8; pass++){
      int c = (t >> 5) + pass * 8;
      f16x8 q8 = *(const f16x8*)(Qb + (size_t)c * 4096 + s0 + so * 8);
      #pragma unroll
      for(int j = 0; j < 8; j++){
        int s = so * 8 + j;
        int col = (((c >> 3) ^ (s & 7)) << 3) | (c & 7);
        Qt[s][col] = q8[j];
      }
    }
  }
  // ---- stage Kt [z][swz c] and Vt [c][swz z] from f32 kagg/vagg ----
  {
    const int z = t >> 2, c0 = (t & 3) * 16;
    #pragma unroll
    for(int u = 0; u < 4; u++){
      float4 v = *(const float4*)(kagg + (size_t)bh * 4096 + z * 64 + c0 + u * 4);
      float vv[4] = {v.x, v.y, v.z, v.w};
      #pragma unroll
      for(int j = 0; j < 4; j++){
        int c = c0 + u * 4 + j;
        int col = (((c >> 3) ^ (z & 7)) << 3) | (c & 7);
        Kt[z][col] = (f16)vv[j];
      }
    }
    #pragma unroll
    for(int u = 0; u < 4; u++){
      float4 v = *(const float4*)(vagg + (size_t)bh * 4096 + z * 64 + c0 + u * 4);
      float vv[4] = {v.x, v.y, v.z, v.w};
      #pragma unroll
      for(int j = 0; j < 4; j++){
        int c = c0 + u * 4 + j;
        int col = (((z >> 3) ^ (c & 7)) << 3) | (z & 7);
        Vt[c][col] = (f16)vv[j];
      }
    }
  }
  __syncthreads();

  // ---- phase 1: logits L[m][z], M=64 rows per wave ----
  f32x4 acc[4][4] = {};
  #pragma unroll
  for(int kc = 0; kc < 2; kc++){
    f16x8 af[4], bf[4];
    #pragma unroll
    for(int mi = 0; mi < 4; mi++){
      int row = w * 64 + mi * 16 + lr;
      af[mi] = *(const f16x8*)(&Qt[row][(((kc * 4 + lg) ^ (row & 7)) << 3)]);
    }
    #pragma unroll
    for(int ni = 0; ni < 4; ni++){
      int row = ni * 16 + lr;
      bf[ni] = *(const f16x8*)(&Kt[row][(((kc * 4 + lg) ^ (row & 7)) << 3)]);
    }
    #pragma unroll
    for(int mi = 0; mi < 4; mi++){
      #pragma unroll
      for(int ni = 0; ni < 4; ni++)
        acc[mi][ni] = mfma16(af[mi], bf[ni], acc[mi][ni]);
    }
  }

  // ---- phase 2: in-register row softmax; P -> wave's own Qt rows (f16, swizzled) ----
  // row m lives in 16 lanes (lr) x 4 fragments (ni); reduce via shfl_xor 1/2/4/8.
  #pragma unroll
  for(int mi = 0; mi < 4; mi++){
    #pragma unroll
    for(int j = 0; j < 4; j++){
      float v0 = acc[mi][0][j], v1 = acc[mi][1][j], v2 = acc[mi][2][j], v3 = acc[mi][3][j];
      float m = fmaxf(fmaxf(v0, v1), fmaxf(v2, v3));
      m = fmaxf(m, __shfl_xor(m, 1)); m = fmaxf(m, __shfl_xor(m, 2));
      m = fmaxf(m, __shfl_xor(m, 4)); m = fmaxf(m, __shfl_xor(m, 8));
      float e0 = expf(v0 - m), e1 = expf(v1 - m), e2 = expf(v2 - m), e3 = expf(v3 - m);
      float sm = e0 + e1 + e2 + e3;
      sm += __shfl_xor(sm, 1); sm += __shfl_xor(sm, 2);
      sm += __shfl_xor(sm, 4); sm += __shfl_xor(sm, 8);
      float inv = 1.f / sm;
      float ev[4] = {e0, e1, e2, e3};
      int row = w * 64 + mi * 16 + lg * 4 + j;
      #pragma unroll
      for(int ni = 0; ni < 4; ni++){
        int z = lr + 16 * ni;
        int col = (((z >> 3) ^ (row & 7)) << 3) | (z & 7);
        Qt[row][col] = (f16)(ev[ni] * inv);
      }
    }
  }
  // no barrier: wave reads/writes only its own Qt rows; Kt/Vt are read-only

  // ---- phase 3: D[m][c] = sum_z P[m][z] V[c][z] ----
  f32x4 acc2[4][4] = {};
  #pragma unroll
  for(int kc = 0; kc < 2; kc++){
    f16x8 af[4], bf[4];
    #pragma unroll
    for(int mi = 0; mi < 4; mi++){
      int row = w * 64 + mi * 16 + lr;
      af[mi] = *(const f16x8*)(&Qt[row][(((kc * 4 + lg) ^ (row & 7)) << 3)]);
    }
    #pragma unroll
    for(int ni = 0; ni < 4; ni++){
      int row = ni * 16 + lr;
      bf[ni] = *(const f16x8*)(&Vt[row][(((kc * 4 + lg) ^ (row & 7)) << 3)]);
    }
    #pragma unroll
    for(int mi = 0; mi < 4; mi++){
      #pragma unroll
      for(int ni = 0; ni < 4; ni++)
        acc2[mi][ni] = mfma16(af[mi], bf[ni], acc2[mi][ni]);
    }
  }

  // ---- output: packed f16x4 along consecutive s (j dimension) ----
  #pragma unroll
  for(int mi = 0; mi < 4; mi++){
    #pragma unroll
    for(int ni = 0; ni < 4; ni++){
      f16x4 o;
      #pragma unroll
      for(int j = 0; j < 4; j++) o[j] = (f16)acc2[mi][ni][j];
      *(f16x4*)(Ob + (size_t)(lr + 16 * ni) * 4096 + s0 + w * 64 + mi * 16 + lg * 4) = o;
    }
  }
}

// ============ 6. PA1 as split-K MFMA GEMM: PA1[x,z] = sum_{c,y} Q[c,x,y]K[c,z,y] ============
__global__ __launch_bounds__(256) void k_pa1(
    const f16* __restrict__ Qh, const f16* __restrict__ Ql,
    const f16* __restrict__ Kh, const f16* __restrict__ Kl,
    float* __restrict__ pa1p)
{
  const int slice = blockIdx.x & 7;
  const int bh = blockIdx.x >> 3;
  const size_t base = (size_t)bh * 64 * 4096;
  __shared__ f16 Ah[2][64][72], Al[2][64][72], Bh[2][64][72], Bl[2][64][72];
  const int t = threadIdx.x;
  const int lane = t & 63, wid = t >> 6;
  const int wm = (wid >> 1) * 32, wn = (wid & 1) * 32;
  const int lr = lane & 15, lg = lane >> 4;
  f32x4 acc[2][2] = {};
  for(int chunk = 0; chunk < 4; chunk++){
    const int c0 = slice * 8 + chunk * 2;
    __syncthreads();
    #pragma unroll
    for(int cc = 0; cc < 2; cc++){
      size_t cbase = base + (size_t)(c0 + cc) * 4096;
      #pragma unroll
      for(int u = 0; u < 2; u++){
        int e = u * 256 + t;
        int x = e >> 3, yh = e & 7;
        size_t src = cbase + (size_t)((x >> 3) * 512 + (x & 7) * 8 + yh * 64);
        int dst = yh * 8;
        *(f16x8*)(&Ah[cc][x][dst]) = *(const f16x8*)(Qh + src);
        *(f16x8*)(&Al[cc][x][dst]) = *(const f16x8*)(Ql + src);
        *(f16x8*)(&Bh[cc][x][dst]) = *(const f16x8*)(Kh + src);
        *(f16x8*)(&Bl[cc][x][dst]) = *(const f16x8*)(Kl + src);
      }
    }
    __syncthreads();
    #pragma unroll
    for(int cc = 0; cc < 2; cc++){
      #pragma unroll
      for(int kc = 0; kc < 2; kc++){
        f16x8 ah[2], alo[2], bh[2], blo[2];
        #pragma unroll
        for(int mi = 0; mi < 2; mi++){
          ah[mi]  = *(const f16x8*)(&Ah[cc][wm + mi * 16 + lr][kc * 32 + lg * 8]);
          alo[mi] = *(const f16x8*)(&Al[cc][wm + mi * 16 + lr][kc * 32 + lg * 8]);
        }
        #pragma unroll
        for(int ni = 0; ni < 2; ni++){
          bh[ni]  = *(const f16x8*)(&Bh[cc][wn + ni * 16 + lr][kc * 32 + lg * 8]);
          blo[ni] = *(const f16x8*)(&Bl[cc][wn + ni * 16 + lr][kc * 32 + lg * 8]);
        }
        #pragma unroll
        for(int mi = 0; mi < 2; mi++){
          #pragma unroll
          for(int ni = 0; ni < 2; ni++){
            f32x4 a = acc[mi][ni];
            a = mfma16(ah[mi],  bh[ni],  a);
            a = mfma16(ah[mi],  blo[ni], a);
            a = mfma16(alo[mi], bh[ni],  a);
            acc[mi][ni] = a;
          }
        }
      }
    }
  }
  float* outp = pa1p + ((size_t)bh * 8 + slice) * 4096;
  #pragma unroll
  for(int mi = 0; mi < 2; mi++){
    #pragma unroll
    for(int ni = 0; ni < 2; ni++){
      #pragma unroll
      for(int j = 0; j < 4; j++){
        int x = wm + mi * 16 + lg * 4 + j;
        int z = wn + ni * 16 + lr;
        outp[x * 64 + z] = acc[mi][ni][j];
      }
    }
  }
}

// ============ 6b. reduce partials + argmax (first max, np semantics) ============
__global__ __launch_bounds__(64) void k_pa1r(
    const float* __restrict__ pa1p, int* __restrict__ idx)
{
  const int bh = blockIdx.x;
  const int x = threadIdx.x;
  const float* p = pa1p + (size_t)bh * 8 * 4096 + x * 64;
  float best = -1e30f; int bi = 0;
  for(int z = 0; z < 64; z += 4){
    float4 v = *(const float4*)(p + z);
    #pragma unroll
    for(int sl = 1; sl < 8; sl++){
      float4 w = *(const float4*)(p + sl * 4096 + z);
      v.x += w.x; v.y += w.y; v.z += w.z; v.w += w.w;
    }
    if(v.x > best){ best = v.x; bi = z; }
    if(v.y > best){ best = v.y; bi = z + 1; }
    if(v.z > best){ best = v.z; bi = z + 2; }
    if(v.w > best){ best = v.w; bi = z + 3; }
  }
  idx[bh * 64 + x] = bi;
}

// ============ 7. PA intra-block attention: 3-phase MFMA (logits / softmax / PV) ============
__global__ __launch_bounds__(256) void k_pa2(
    const f16* __restrict__ Qh, const f16* __restrict__ Kh,
    const f16* __restrict__ V2, const int* __restrict__ idx, f16* __restrict__ Out)
{
  // XCD swizzle: all 64 x-blocks of one bh land on one XCD (hw%8 assumed = XCD)
  const int hw = blockIdx.x;
  const int bh = (hw & 7) * 4 + ((hw >> 3) >> 6);
  const int x  = (hw >> 3) & 63;
  const size_t base = (size_t)bh * 64 * 4096;
  f16* Ob = Out + base;

  // Qt/Kt (f16 transposed, XOR-swizzled) overlaid later by Lf (f32 logits) then Os (f32 out)
  __shared__ __align__(16) char Ubuf[18432];
  __shared__ f16 Vn[64][72];   // V[c][z], natural layout
  __shared__ f16 Ps[64][72];   // P[y][z]
  f16   (*Qt)[72] = (f16(*)[72])Ubuf;            // Qt[y][swz(c)]
  f16   (*Kt)[72] = (f16(*)[72])(Ubuf + 9216);   // Kt[z][swz(c)]
  float (*Lf)[66] = (float(*)[66])Ubuf;          // logits [y][z]
  float (*Os)[67] = (float(*)[67])Ubuf;          // out staging [c][y]

  const int t = threadIdx.x;
  const int lane = t & 63, wid = t >> 6;
  const int wm = (wid >> 1) * 32, wn = (wid & 1) * 32;
  const int lr = lane & 15, lg = lane >> 4;

  const int xk = idx[bh * 64 + x];
  const int xb = (x >> 3) * 512 + (x & 7) * 8;
  const int kb = (xk >> 3) * 512 + (xk & 7) * 8;

  // ---- stage: Q,K transposed+swizzled; V natural ----
  {
    const int c = t >> 2, q4 = t & 3;
    #pragma unroll
    for(int u = 0; u < 2; u++){
      int yh = q4 * 2 + u;
      f16x8 q8 = *(const f16x8*)(Qh + base + (size_t)c * 4096 + xb + yh * 64);
      f16x8 k8 = *(const f16x8*)(Kh + base + (size_t)c * 4096 + kb + yh * 64);
      f16x8 v8 = *(const f16x8*)(V2 + base + (size_t)c * 4096 + kb + yh * 64);
      int col = ((((c >> 3) ^ yh) & 7) << 3) + (c & 7);  // conflict-free scatter
      #pragma unroll
      for(int j = 0; j < 8; j++){
        Qt[yh * 8 + j][col] = q8[j];
        Kt[yh * 8 + j][col] = k8[j];
      }
      *(f16x8*)(&Vn[c][yh * 8]) = v8;
    }
  }
  __syncthreads();

  // ---- phase 1: L[y][z] = sum_c Q[y][c] K[z][c] ----
  f32x4 acc[2][2] = {};
  #pragma unroll
  for(int kc = 0; kc < 2; kc++){
    f16x8 af[2], bf[2];
    #pragma unroll
    for(int mi = 0; mi < 2; mi++){
      int row = wm + mi * 16 + lr;
      af[mi] = *(const f16x8*)(&Qt[row][((((kc * 4 + lg) ^ (row >> 3)) & 7) << 3)]);
    }
    #pragma unroll
    for(int ni = 0; ni < 2; ni++){
      int row = wn + ni * 16 + lr;
      bf[ni] = *(const f16x8*)(&Kt[row][((((kc * 4 + lg) ^ (row >> 3)) & 7) << 3)]);
    }
    #pragma unroll
    for(int mi = 0; mi < 2; mi++){
      #pragma unroll
      for(int ni = 0; ni < 2; ni++)
        acc[mi][ni] = mfma16(af[mi], bf[ni], acc[mi][ni]);
    }
  }
  __syncthreads();  // all Qt/Kt reads done before Lf overlay write
  #pragma unroll
  for(int mi = 0; mi < 2; mi++){
    #pragma unroll
    for(int ni = 0; ni < 2; ni++){
      #pragma unroll
      for(int j = 0; j < 4; j++)
        Lf[wm + mi * 16 + lg * 4 + j][wn + ni * 16 + lr] = acc[mi][ni][j];
    }
  }
  __syncthreads();

  // ---- phase 2: row softmax (4 threads per row, 16 z each) ----
  {
    const int y = t >> 2, zp = t & 3;
    float l[16];
    #pragma unroll
    for(int i = 0; i < 16; i++) l[i] = Lf[y][zp * 16 + i];
    float m = l[0];
    #pragma unroll
    for(int i = 1; i < 16; i++) m = fmaxf(m, l[i]);
    m = fmaxf(m, __shfl_xor(m, 1)); m = fmaxf(m, __shfl_xor(m, 2));
    float sum = 0.f;
    #pragma unroll
    for(int i = 0; i < 16; i++){ l[i] = expf(l[i] - m); sum += l[i]; }
    sum += __shfl_xor(sum, 1); sum += __shfl_xor(sum, 2);
    float inv = 1.f / sum;
    f16x8 p0, p1;
    #pragma unroll
    for(int i = 0; i < 8; i++){ p0[i] = (f16)(l[i] * inv); p1[i] = (f16)(l[8 + i] * inv); }
    *(f16x8*)(&Ps[y][zp * 16]) = p0;
    *(f16x8*)(&Ps[y][zp * 16 + 8]) = p1;
  }
  __syncthreads();  // Ps visible; Lf reads done -> Os overlay safe

  // ---- phase 3: D[y][c] = sum_z P[y][z] V[c][z] ----
  f32x4 acc2[2][2] = {};
  #pragma unroll
  for(int kc = 0; kc < 2; kc++){
    f16x8 af[2], bf[2];
    #pragma unroll
    for(int mi = 0; mi < 2; mi++)
      af[mi] = *(const f16x8*)(&Ps[wm + mi * 16 + lr][kc * 32 + lg * 8]);
    #pragma unroll
    for(int ni = 0; ni < 2; ni++)
      bf[ni] = *(const f16x8*)(&Vn[wn + ni * 16 + lr][kc * 32 + lg * 8]);
    #pragma unroll
    for(int mi = 0; mi < 2; mi++){
      #pragma unroll
      for(int ni = 0; ni < 2; ni++)
        acc2[mi][ni] = mfma16(af[mi], bf[ni], acc2[mi][ni]);
    }
  }
  #pragma unroll
  for(int mi = 0; mi < 2; mi++){
    #pragma unroll
    for(int ni = 0; ni < 2; ni++){
      #pragma unroll
      for(int j = 0; j < 4; j++)
        Os[wn + ni * 16 + lr][wm + mi * 16 + lg * 4 + j] = acc2[mi][ni][j];
    }
  }
  __syncthreads();

  // ---- output: coalesced f16x8 stores ----
  {
    const int c = t >> 2, yp = t & 3;
    #pragma unroll
    for(int u = 0; u < 2; u++){
      int yh = yp * 2 + u;
      f16x8 w;
      #pragma unroll
      for(int j = 0; j < 8; j++) w[j] = (f16)Os[c][yh * 8 + j];
      *(f16x8*)(Ob + (size_t)c * 4096 + xb + yh * 64) = w;
    }
  }
}

// ============ 8. Fused output: f1*DA + f2*PA + biases + content -> f32 ============
__global__ __launch_bounds__(256) void k_final(
    const f16* __restrict__ X1, const float* __restrict__ W1, const float* __restrict__ B1,
    const f16* __restrict__ X2, const float* __restrict__ W2, const float* __restrict__ B2,
    const float* __restrict__ content, float* __restrict__ out)
{
  const int b = blockIdx.z;
  const int o0 = blockIdx.y * 128;
  const int s0 = blockIdx.x * 128;
  __shared__ f16 As[128 * LSTR];
  __shared__ f16 Bs[128 * LSTR];
  const int t = threadIdx.x;
  const int lane = t & 63, wid = t >> 6;
  const int wm = (wid >> 1) * 64, wn = (wid & 1) * 64;
  const int lr = lane & 15, lg = lane >> 4;
  f32x4 acc[4][4] = {};
  for(int pass = 0; pass < 2; pass++){
    const f16* Xb = (pass ? X2 : X1) + (size_t)b * 512 * 4096;
    const float* Wp = pass ? W2 : W1;
    for(int kk = 0; kk < 512; kk += 32){
      __syncthreads();
      #pragma unroll
      for(int rep = 0; rep < 4; rep++){
        int q = t + 256 * rep;
        int row = q >> 3, c4 = q & 7;
        float4 w4 = *(const float4*)(Wp + (size_t)(o0 + row) * 512 + kk + c4 * 4);
        f16* dst = As + row * LSTR + c4 * 4;
        dst[0] = (f16)w4.x; dst[1] = (f16)w4.y; dst[2] = (f16)w4.z; dst[3] = (f16)w4.w;
      }
      #pragma unroll
      for(int rep = 0; rep < 2; rep++){
        int q = t + 256 * rep;
        int kr = q >> 4, s8 = q & 15;
        f16x8 v = *(const f16x8*)(Xb + (size_t)(kk + kr) * 4096 + s0 + s8 * 8);
        #pragma unroll
        for(int j = 0; j < 8; j++){
          int jj = (j + s8) & 7;
          Bs[(s8 * 8 + jj) * LSTR + kr] = v[jj];
        }
      }
      __syncthreads();
      f16x8 av[4], bv[4];
      #pragma unroll
      for(int mi = 0; mi < 4; mi++)
        av[mi] = *(const f16x8*)(As + (wm + mi * 16 + lr) * LSTR + lg * 8);
      #pragma unroll
      for(int ni = 0; ni < 4; ni++)
        bv[ni] = *(const f16x8*)(Bs + (wn + ni * 16 + lr) * LSTR + lg * 8);
      #pragma unroll
      for(int mi = 0; mi < 4; mi++){
        #pragma unroll
        for(int ni = 0; ni < 4; ni++)
          acc[mi][ni] = mfma16(av[mi], bv[ni], acc[mi][ni]);
      }
    }
  }
  #pragma unroll
  for(int mi = 0; mi < 4; mi++){
    #pragma unroll
    for(int ni = 0; ni < 4; ni++){
      #pragma unroll
      for(int j = 0; j < 4; j++){
        int o = o0 + wm + mi * 16 + lg * 4 + j;
        int s = s0 + wn + ni * 16 + lr;
        size_t gi = ((size_t)b * 512 + o) * 4096 + s;
        out[gi] = acc[mi][ni][j] + B1[o] + B2[o] + content[gi];
      }
    }
  }
}

extern "C" void kernel_launch(void* const* d_in, const int* in_sizes, int n_in,
                              void* d_out, int out_size, void* d_ws, size_t ws_size,
                              hipStream_t stream) {
  (void)in_sizes; (void)n_in; (void)out_size; (void)ws_size;
  const float* content = (const float*)d_in[0];
  const float* style   = (const float*)d_in[1];
  const float* q_w  = (const float*)d_in[2];  const float* q_b  = (const float*)d_in[3];
  const float* k_w  = (const float*)d_in[4];  const float* k_b  = (const float*)d_in[5];
  const float* v_w  = (const float*)d_in[6];  const float* v_b  = (const float*)d_in[7];
  const float* q2_w = (const float*)d_in[8];  const float* q2_b = (const float*)d_in[9];
  const float* k2_w = (const float*)d_in[10]; const float* k2_b = (const float*)d_in[11];
  const float* v2_w = (const float*)d_in[12]; const float* v2_b = (const float*)d_in[13];
  const float* f1_w = (const float*)d_in[14]; const float* f1_b = (const float*)d_in[15];
  const float* f2_w = (const float*)d_in[16]; const float* f2_b = (const float*)d_in[17];
  const float* sim_alpha = (const float*)d_in[18];
  const float* sim_beta  = (const float*)d_in[19];

  char* ws = (char*)d_ws;
  f16*   q2h  = (f16*)(ws + 0);                // 16,777,216 B
  f16*   q2l  = (f16*)(ws + 16777216);         // 16,777,216 B
  f16*   k2h  = (f16*)(ws + 33554432);         // 16,777,216 B
  f16*   k2l  = (f16*)(ws + 50331648);         // 16,777,216 B
  f16*   qbuf = (f16*)(ws + 67108864);         // 16,777,216 B
  f16*   kbuf = (f16*)(ws + 83886080);         // 16,777,216 B
  f16*   vbuf = (f16*)(ws + 100663296);        // 16,777,216 B
  f16*   dabuf= (f16*)(ws + 117440512);        // 16,777,216 B
  f16*   v2buf= (f16*)(ws + 67108864);         // reuses qbuf slot (after da2)
  f16*   pabuf= (f16*)(ws + 83886080);         // reuses kbuf slot (after da1)
  float* pa1p = (float*)(ws + 100663296);      // reuses vbuf slot (after da1), 4 MB
  float* stats= (float*)(ws + 134217728);      // 32,768 B
  float* kagg = (float*)(ws + 134250496);      // 524,288 B
  float* vagg = (float*)(ws + 134774784);      // 524,288 B
  int*   idxb = (int*)(ws + 135299072);        // 8,192 B

  dim3 gconv(32, 4, 4);

  k_mvn_stats<<<4096, 256, 0, stream>>>(content, style, stats);

  // precision-critical path (feeds argmax): fp16-split, hi/lo f16 outputs
  k_conv_hp<<<gconv, 256, 0, stream>>>(content, q2_w, q2_b, stats, 0,    q2h, q2l);
  k_conv_hp<<<gconv, 256, 0, stream>>>(style,   k2_w, k2_b, stats, 4096, k2h, k2l);

  // softmax-tolerant paths: plain fp16
  k_conv_h<<<gconv, 256, 0, stream>>>(content, q_w, q_b, stats, 0,    qbuf);
  k_conv_h<<<gconv, 256, 0, stream>>>(style,   k_w, k_b, stats, 4096, kbuf);
  k_conv_h<<<gconv, 256, 0, stream>>>(style,   v_w, v_b, stats, -1,   vbuf);

  k_da1<<<2048, 256, 0, stream>>>(kbuf, vbuf, sim_alpha, sim_beta, kagg, vagg);
  k_da2<<<512, 256, 0, stream>>>(qbuf, kagg, vagg, dabuf);

  k_conv_h<<<gconv, 256, 0, stream>>>(style, v2_w, v2_b, stats, -1, v2buf); // after da2 (reuses q slot)

  k_pa1<<<256, 256, 0, stream>>>(q2h, q2l, k2h, k2l, pa1p);   // after da1 (pa1p reuses v slot)
  k_pa1r<<<32, 64, 0, stream>>>(pa1p, idxb);
  k_pa2<<<2048, 256, 0, stream>>>(q2h, k2h, v2buf, idxb, pabuf);

  k_final<<<gconv, 256, 0, stream>>>(dabuf, f1_w, f1_b, pabuf, f2_w, f2_b,
                                     content, (float*)d_out);
}